// Round 1
// baseline (1888.808 us; speedup 1.0000x reference)
//
#include <hip/hip_runtime.h>
#include <math.h>

#define N_TOK 4096
#define DM 1024
#define DFF 4096
#define DN 128
#define NH 8
#define HD 16
#define KSEL 32

__device__ __forceinline__ float gelu_f(float x) {
  return 0.5f * x * (1.0f + erff(x * 0.70710678118654752440f));
}

// ---------------- LayerNorm: xn = (x-mu)*rsqrt(var+eps)*g + b ----------------
__global__ __launch_bounds__(256) void ln_kernel(const float* __restrict__ x,
    const float* __restrict__ g, const float* __restrict__ b, float* __restrict__ xn) {
  int n = blockIdx.x, tid = threadIdx.x;
  const float* row = x + (size_t)n * DM;
  float s = 0.f, sq = 0.f;
  for (int i = tid; i < DM; i += 256) { float v = row[i]; s += v; sq += v * v; }
  for (int off = 32; off; off >>= 1) { s += __shfl_down(s, off); sq += __shfl_down(sq, off); }
  __shared__ float ss[4], ssq[4];
  __shared__ float s_mu, s_rs;
  int wid = tid >> 6;
  if ((tid & 63) == 0) { ss[wid] = s; ssq[wid] = sq; }
  __syncthreads();
  if (tid == 0) {
    float S = ss[0] + ss[1] + ss[2] + ss[3];
    float Q = ssq[0] + ssq[1] + ssq[2] + ssq[3];
    float mu = S * (1.f / DM);
    float var = Q * (1.f / DM) - mu * mu;
    s_mu = mu; s_rs = rsqrtf(var + 1e-5f);
  }
  __syncthreads();
  float mu = s_mu, rs = s_rs;
  float* o = xn + (size_t)n * DM;
  for (int i = tid; i < DM; i += 256) o[i] = (row[i] - mu) * rs * g[i] + b[i];
}

// ---------------- fp32 GEMM: C[M,N] = act(A[M,K] @ B[N,K]^T) ----------------
// 128x128 tile, TK=32, 256 threads, 8x8 micro-tile per thread. Dims divide evenly.
__global__ __launch_bounds__(256) void gemm_nt(const float* __restrict__ A,
    const float* __restrict__ B, float* __restrict__ C, int M, int N, int K, int act) {
  __shared__ float As[128 * 33];
  __shared__ float Bs[128 * 33];
  int tid = threadIdx.x;
  int tx = tid & 15, ty = tid >> 4;
  const float* Ab = A + (size_t)blockIdx.y * 128 * K;
  const float* Bb = B + (size_t)blockIdx.x * 128 * K;
  float acc[8][8] = {};
  for (int k0 = 0; k0 < K; k0 += 32) {
#pragma unroll
    for (int i = 0; i < 16; i++) {
      int l = tid + i * 256;
      int r = l >> 5, c = l & 31;
      As[r * 33 + c] = Ab[(size_t)r * K + k0 + c];
      Bs[r * 33 + c] = Bb[(size_t)r * K + k0 + c];
    }
    __syncthreads();
#pragma unroll
    for (int kk = 0; kk < 32; kk++) {
      float a[8], b[8];
#pragma unroll
      for (int i = 0; i < 8; i++) a[i] = As[(ty * 8 + i) * 33 + kk];
#pragma unroll
      for (int i = 0; i < 8; i++) b[i] = Bs[(tx * 8 + i) * 33 + kk];
#pragma unroll
      for (int i = 0; i < 8; i++)
#pragma unroll
        for (int j = 0; j < 8; j++)
          acc[i][j] = fmaf(a[i], b[j], acc[i][j]);
    }
    __syncthreads();
  }
  for (int i = 0; i < 8; i++) {
    size_t m = (size_t)blockIdx.y * 128 + ty * 8 + i;
    float* Cr = C + m * N + (size_t)blockIdx.x * 128 + tx * 8;
#pragma unroll
    for (int j = 0; j < 8; j++) {
      float v = acc[i][j];
      if (act) v = gelu_f(v);
      Cr[j] = v;
    }
  }
}

// ------- per-neuron qkv table: tab[f][r] = ipb[r] + sum_c nv[f][c]*ipw[r][c] -------
__global__ __launch_bounds__(384) void qkvtab_kernel(const float* __restrict__ nv,
    const float* __restrict__ ipw, const float* __restrict__ ipb, float* __restrict__ tab) {
  __shared__ float s_nv[8 * 128];
  int f0 = blockIdx.x * 8;
  int tid = threadIdx.x;
  for (int i = tid; i < 8 * 128; i += 384) s_nv[i] = nv[(size_t)f0 * 128 + i];
  __syncthreads();
  int row = tid;  // < 384
  float bias = ipb[row];
  float acc[8];
#pragma unroll
  for (int ff = 0; ff < 8; ff++) acc[ff] = bias;
  const float* wr = ipw + (size_t)row * 128;
  for (int c = 0; c < 128; c++) {
    float w = wr[c];
#pragma unroll
    for (int ff = 0; ff < 8; ff++) acc[ff] = fmaf(s_nv[ff * 128 + c], w, acc[ff]);
  }
#pragma unroll
  for (int ff = 0; ff < 8; ff++) tab[(size_t)(f0 + ff) * 384 + row] = acc[ff];
}

// ---------------- top-32 per row via 32x iterative argmax ----------------
__global__ __launch_bounds__(256) void topk_kernel(const float* __restrict__ scores,
    int* __restrict__ idxo) {
  __shared__ float sv[DFF];
  __shared__ float wrv[4];
  __shared__ int wri[4];
  int n = blockIdx.x, tid = threadIdx.x;
  const float* row = scores + (size_t)n * DFF;
  for (int i = tid; i < DFF; i += 256) sv[i] = row[i];
  __syncthreads();
  for (int it = 0; it < KSEL; it++) {
    float bv = -INFINITY;
    int bi = 0x7fffffff;
    for (int i = tid; i < DFF; i += 256) {
      float v = sv[i];
      if (v > bv) { bv = v; bi = i; }   // ascending scan keeps lowest index on ties
    }
    for (int off = 32; off; off >>= 1) {
      float ov = __shfl_down(bv, off);
      int oi = __shfl_down(bi, off);
      if (ov > bv || (ov == bv && oi < bi)) { bv = ov; bi = oi; }
    }
    int wid = tid >> 6;
    if ((tid & 63) == 0) { wrv[wid] = bv; wri[wid] = bi; }
    __syncthreads();
    if (tid == 0) {
      float fv = wrv[0]; int fi = wri[0];
      for (int w = 1; w < 4; w++)
        if (wrv[w] > fv || (wrv[w] == fv && wri[w] < fi)) { fv = wrv[w]; fi = wri[w]; }
      idxo[(size_t)n * KSEL + it] = fi;
      sv[fi] = -INFINITY;
    }
    __syncthreads();
  }
}

// ---------------- fused per-token tail: base, attention, out_proj, gate, output ----------------
__global__ __launch_bounds__(256) void tail_kernel(
    const float* __restrict__ xf, const float* __restrict__ pats,
    const float* __restrict__ dirs, const float* __restrict__ qkvtab,
    const int* __restrict__ idxs,
    const float* __restrict__ opw, const float* __restrict__ opb,
    const float* __restrict__ w1, const float* __restrict__ b1,
    const float* __restrict__ w2, const float* __restrict__ b2,
    float* __restrict__ out) {
  __shared__ float s_xf[1024];
  __shared__ float s_ao[32 * 129];   // attention output, padded stride 129
  __shared__ float s_at[32 * 129];   // attended (out_proj result), stride 129
  __shared__ float s_scr[2688];      // q(544) k(544) v(544) att(1056); later hid (32*65)
  __shared__ float s_w[4224];        // weight staging
  __shared__ float s_base[32];
  __shared__ float s_coef[32];
  __shared__ int s_idx[32];

  int n = blockIdx.x, tid = threadIdx.x;
  if (tid < 32) s_idx[tid] = idxs[(size_t)n * 32 + tid];
  for (int i = tid; i < 1024; i += 256) s_xf[i] = xf[(size_t)n * 1024 + i];
  __syncthreads();

  // base[g] = gelu(xf . pats[idx[g]]) — 32 groups x 8 lanes
  {
    int g = tid >> 3, l = tid & 7;
    const float* pr = pats + (size_t)s_idx[g] * 1024;
    float s = 0.f;
    for (int c = l; c < 1024; c += 8) s = fmaf(s_xf[c], pr[c], s);
    s += __shfl_down(s, 4, 8);
    s += __shfl_down(s, 2, 8);
    s += __shfl_down(s, 1, 8);
    if (l == 0) s_base[g] = gelu_f(s);
  }

  float* s_q = s_scr;
  float* s_k = s_scr + 544;
  float* s_v = s_scr + 1088;
  float* s_att = s_scr + 1632;  // stride 33

  for (int h = 0; h < NH; h++) {
    __syncthreads();  // guard s_scr overwrite vs previous head's reads
    // gather q,k,v head slices from the per-neuron table
#pragma unroll
    for (int p = 0; p < 6; p++) {
      int o = tid + p * 256;         // < 1536
      int m = o >> 9;                // 0=q 1=k 2=v
      int r = o & 511;
      int j = r & 31, d = r >> 5;    // lanes: j fastest -> broadcast-friendly
      s_scr[m * 544 + j * 17 + d] =
          qkvtab[(size_t)s_idx[j] * 384 + m * 128 + h * 16 + d];
    }
    __syncthreads();
    // att[qj][kj] = q.k / 4
#pragma unroll
    for (int p = 0; p < 4; p++) {
      int e = tid + p * 256;
      int qj = e >> 5, kj = e & 31;
      float s = 0.f;
#pragma unroll
      for (int d = 0; d < 16; d++) s = fmaf(s_q[qj * 17 + d], s_k[kj * 17 + d], s);
      s_att[qj * 33 + kj] = s * 0.25f;
    }
    __syncthreads();
    // softmax per row: 8 lanes per row
    {
      int r = tid >> 3, l = tid & 7;
      float m = -INFINITY;
      for (int k = l; k < 32; k += 8) m = fmaxf(m, s_att[r * 33 + k]);
      m = fmaxf(m, __shfl_xor(m, 4, 8));
      m = fmaxf(m, __shfl_xor(m, 2, 8));
      m = fmaxf(m, __shfl_xor(m, 1, 8));
      float sum = 0.f;
      for (int k = l; k < 32; k += 8) {
        float e = expf(s_att[r * 33 + k] - m);
        s_att[r * 33 + k] = e;
        sum += e;
      }
      sum += __shfl_xor(sum, 4, 8);
      sum += __shfl_xor(sum, 2, 8);
      sum += __shfl_xor(sum, 1, 8);
      float inv = 1.f / sum;
      for (int k = l; k < 32; k += 8) s_att[r * 33 + k] *= inv;
    }
    __syncthreads();
    // ao[j][h*16+d] = sum_k att[j][k] * v[k][d]
#pragma unroll
    for (int p = 0; p < 2; p++) {
      int o = tid + p * 256;
      int d = o & 15, j = o >> 4;
      float a = 0.f;
#pragma unroll
      for (int k = 0; k < 32; k++) a = fmaf(s_att[j * 33 + k], s_v[k * 17 + d], a);
      s_ao[j * 129 + h * 16 + d] = a;
    }
  }
  __syncthreads();

  // attended = ao @ opw^T + opb ; 4x4 register tiles, r = tr + 32*jj (conflict-free)
  int tj = tid >> 5;   // 0..7 -> j block
  int tr = tid & 31;   // 0..31 -> r lane
  float acc[4][4];
#pragma unroll
  for (int i = 0; i < 4; i++)
#pragma unroll
    for (int jj = 0; jj < 4; jj++) acc[i][jj] = opb[tr + 32 * jj];
  for (int cq = 0; cq < 4; cq++) {
    for (int t = tid; t < 4096; t += 256) {
      int r = t >> 5, cc = t & 31;
      s_w[r * 33 + cc] = opw[(size_t)r * 128 + cq * 32 + cc];
    }
    __syncthreads();
#pragma unroll
    for (int cc = 0; cc < 32; cc++) {
      float a4[4], w4[4];
#pragma unroll
      for (int i = 0; i < 4; i++) a4[i] = s_ao[(tj * 4 + i) * 129 + cq * 32 + cc];
#pragma unroll
      for (int jj = 0; jj < 4; jj++) w4[jj] = s_w[(tr + 32 * jj) * 33 + cc];
#pragma unroll
      for (int i = 0; i < 4; i++)
#pragma unroll
        for (int jj = 0; jj < 4; jj++) acc[i][jj] = fmaf(a4[i], w4[jj], acc[i][jj]);
    }
    __syncthreads();
  }
#pragma unroll
  for (int i = 0; i < 4; i++)
#pragma unroll
    for (int jj = 0; jj < 4; jj++)
      s_at[(tj * 4 + i) * 129 + tr + 32 * jj] = acc[i][jj];
  __syncthreads();

  // gate hidden: hid = gelu(attended @ w1^T + b1), rows staged in halves of 32
  for (int half = 0; half < 2; half++) {
    for (int t = tid; t < 4096; t += 256) {
      int r = t >> 7, c = t & 127;
      s_w[r * 129 + c] = w1[(size_t)(half * 32 + r) * 128 + c];
    }
    __syncthreads();
    float a4[4];
    float bb = b1[half * 32 + tr];
#pragma unroll
    for (int i = 0; i < 4; i++) a4[i] = bb;
    for (int c = 0; c < 128; c++) {
      float w = s_w[tr * 129 + c];
#pragma unroll
      for (int i = 0; i < 4; i++) a4[i] = fmaf(s_at[(tj * 4 + i) * 129 + c], w, a4[i]);
    }
#pragma unroll
    for (int i = 0; i < 4; i++)
      s_scr[(tj * 4 + i) * 65 + half * 32 + tr] = gelu_f(a4[i]);  // hid, stride 65
    __syncthreads();
  }

  // wp2 + sigmoid -> coef = base * sw
  if (tid < 32) {
    float a = b2[0];
    for (int r = 0; r < 64; r++) a = fmaf(s_scr[tid * 65 + r], w2[r], a);
    float sw = 1.f / (1.f + expf(-a));
    s_coef[tid] = s_base[tid] * sw;
  }
  __syncthreads();

  // out[n][d] = sum_j coef[j] * dirs[idx[j]][d]
#pragma unroll
  for (int p = 0; p < 4; p++) {
    int d = tid + p * 256;
    float a = 0.f;
    for (int j = 0; j < 32; j++)
      a = fmaf(s_coef[j], dirs[(size_t)s_idx[j] * 1024 + d], a);
    out[(size_t)n * 1024 + d] = a;
  }
}

extern "C" void kernel_launch(void* const* d_in, const int* in_sizes, int n_in,
                              void* d_out, int out_size, void* d_ws, size_t ws_size,
                              hipStream_t stream) {
  const float* x    = (const float*)d_in[0];
  const float* pats = (const float*)d_in[1];
  const float* nv   = (const float*)d_in[2];
  const float* dirs = (const float*)d_in[3];
  const float* rw1  = (const float*)d_in[4];
  const float* rw2  = (const float*)d_in[5];
  const float* lng  = (const float*)d_in[6];
  const float* lnb  = (const float*)d_in[7];
  const float* ipw  = (const float*)d_in[8];
  const float* ipb  = (const float*)d_in[9];
  const float* opw  = (const float*)d_in[10];
  const float* opb  = (const float*)d_in[11];
  const float* w1   = (const float*)d_in[12];
  const float* b1   = (const float*)d_in[13];
  const float* w2   = (const float*)d_in[14];
  const float* b2   = (const float*)d_in[15];
  float* out = (float*)d_out;

  // workspace layout (fp32): xn | h | scores | qkv_tab | idx  (~103 MB)
  float* xn     = (float*)d_ws;
  float* hbuf   = xn + (size_t)N_TOK * DM;
  float* scores = hbuf + (size_t)N_TOK * DM;
  float* qtab   = scores + (size_t)N_TOK * DFF;
  int*   idxb   = (int*)(qtab + (size_t)DFF * 384);

  ln_kernel<<<N_TOK, 256, 0, stream>>>(x, lng, lnb, xn);
  gemm_nt<<<dim3(DM / 128, N_TOK / 128), 256, 0, stream>>>(xn, rw1, hbuf, N_TOK, DM, DM, 1);
  gemm_nt<<<dim3(DFF / 128, N_TOK / 128), 256, 0, stream>>>(hbuf, rw2, scores, N_TOK, DFF, DM, 0);
  qkvtab_kernel<<<DFF / 8, 384, 0, stream>>>(nv, ipw, ipb, qtab);
  topk_kernel<<<N_TOK, 256, 0, stream>>>(scores, idxb);
  tail_kernel<<<N_TOK, 256, 0, stream>>>(x, pats, dirs, qtab, idxb,
                                         opw, opb, w1, b1, w2, b2, out);
}

// Round 2
// 1214.901 us; speedup vs baseline: 1.5547x; 1.5547x over previous
//
#include <hip/hip_runtime.h>
#include <hip/hip_bf16.h>
#include <math.h>

#define N_TOK 4096
#define DM 1024
#define DFF 4096
#define DN 128
#define NH 8
#define HD 16
#define KSEL 32
#define KCAND 48

typedef __attribute__((ext_vector_type(4))) float floatx4;
typedef __attribute__((ext_vector_type(8))) short short8;

__device__ __forceinline__ float gelu_f(float x) {
  return 0.5f * x * (1.0f + erff(x * 0.70710678118654752440f));
}

// ---------------- LayerNorm ----------------
__global__ __launch_bounds__(256) void ln_kernel(const float* __restrict__ x,
    const float* __restrict__ g, const float* __restrict__ b, float* __restrict__ xn) {
  int n = blockIdx.x, tid = threadIdx.x;
  const float* row = x + (size_t)n * DM;
  float s = 0.f, sq = 0.f;
  for (int i = tid; i < DM; i += 256) { float v = row[i]; s += v; sq += v * v; }
  for (int off = 32; off; off >>= 1) { s += __shfl_down(s, off); sq += __shfl_down(sq, off); }
  __shared__ float ss[4], ssq[4];
  __shared__ float s_mu, s_rs;
  int wid = tid >> 6;
  if ((tid & 63) == 0) { ss[wid] = s; ssq[wid] = sq; }
  __syncthreads();
  if (tid == 0) {
    float S = ss[0] + ss[1] + ss[2] + ss[3];
    float Q = ssq[0] + ssq[1] + ssq[2] + ssq[3];
    float mu = S * (1.f / DM);
    float var = Q * (1.f / DM) - mu * mu;
    s_mu = mu; s_rs = rsqrtf(var + 1e-5f);
  }
  __syncthreads();
  float mu = s_mu, rs = s_rs;
  float* o = xn + (size_t)n * DM;
  for (int i = tid; i < DM; i += 256) o[i] = (row[i] - mu) * rs * g[i] + b[i];
}

// ---------------- fp32 GEMM (gemm1 only): C = gelu(A@B^T), also emits bf16 copy ----------------
__global__ __launch_bounds__(256) void gemm_nt(const float* __restrict__ A,
    const float* __restrict__ B, float* __restrict__ C, __hip_bfloat16* __restrict__ Cb,
    int M, int N, int K, int act) {
  __shared__ float As[128 * 33];
  __shared__ float Bs[128 * 33];
  int tid = threadIdx.x;
  int tx = tid & 15, ty = tid >> 4;
  const float* Ab = A + (size_t)blockIdx.y * 128 * K;
  const float* Bb = B + (size_t)blockIdx.x * 128 * K;
  float acc[8][8] = {};
  for (int k0 = 0; k0 < K; k0 += 32) {
#pragma unroll
    for (int i = 0; i < 16; i++) {
      int l = tid + i * 256;
      int r = l >> 5, c = l & 31;
      As[r * 33 + c] = Ab[(size_t)r * K + k0 + c];
      Bs[r * 33 + c] = Bb[(size_t)r * K + k0 + c];
    }
    __syncthreads();
#pragma unroll
    for (int kk = 0; kk < 32; kk++) {
      float a[8], b[8];
#pragma unroll
      for (int i = 0; i < 8; i++) a[i] = As[(ty * 8 + i) * 33 + kk];
#pragma unroll
      for (int i = 0; i < 8; i++) b[i] = Bs[(tx * 8 + i) * 33 + kk];
#pragma unroll
      for (int i = 0; i < 8; i++)
#pragma unroll
        for (int j = 0; j < 8; j++)
          acc[i][j] = fmaf(a[i], b[j], acc[i][j]);
    }
    __syncthreads();
  }
  for (int i = 0; i < 8; i++) {
    size_t m = (size_t)blockIdx.y * 128 + ty * 8 + i;
    size_t cb = m * N + (size_t)blockIdx.x * 128 + tx * 8;
#pragma unroll
    for (int j = 0; j < 8; j++) {
      float v = acc[i][j];
      if (act) v = gelu_f(v);
      C[cb + j] = v;
      if (Cb) Cb[cb + j] = __float2bfloat16(v);
    }
  }
}

// ---------------- fp32 -> bf16 convert ----------------
__global__ __launch_bounds__(256) void cvt_bf16(const float* __restrict__ in,
    __hip_bfloat16* __restrict__ out, int n4) {
  int i = (blockIdx.x * 256 + threadIdx.x) * 4;
  float4 v = *(const float4*)(in + i);
  out[i + 0] = __float2bfloat16(v.x);
  out[i + 1] = __float2bfloat16(v.y);
  out[i + 2] = __float2bfloat16(v.z);
  out[i + 3] = __float2bfloat16(v.w);
}

// ---------------- bf16 MFMA GEMM: scores_approx = hb @ w2b^T ----------------
// m97 structure: 128x128 tile, BK=32, global_load_lds width 16, XOR-swizzled LDS.
__global__ __launch_bounds__(256) void gemm_bf(const __hip_bfloat16* __restrict__ Ah,
    const __hip_bfloat16* __restrict__ Bh, float* __restrict__ C) {
  __shared__ short Asd[128 * 32];
  __shared__ short Bsd[128 * 32];
  const int K = 1024;
  int tid = threadIdx.x;
  int w = tid >> 6, l = tid & 63;
  size_t brow = (size_t)blockIdx.y * 128;
  size_t bcol = (size_t)blockIdx.x * 128;
  const short* Ab = (const short*)Ah + brow * K;
  const short* Bb = (const short*)Bh + bcol * K;

  // staging: wave w stages rows [w*32, w*32+32) of each tile; 2 instrs of 16 rows.
  int r0 = w * 32 + (l >> 2);
  int g0 = (l & 3) ^ ((r0 >> 1) & 3);   // same for r0 and r0+16
  const short* Ag0 = Ab + (size_t)r0 * K + g0 * 8;
  const short* Ag1 = Ab + (size_t)(r0 + 16) * K + g0 * 8;
  const short* Bg0 = Bb + (size_t)r0 * K + g0 * 8;
  const short* Bg1 = Bb + (size_t)(r0 + 16) * K + g0 * 8;
  short* ALds0 = &Asd[w * 1024];
  short* ALds1 = &Asd[w * 1024 + 512];
  short* BLds0 = &Bsd[w * 1024];
  short* BLds1 = &Bsd[w * 1024 + 512];

  // fragment read addresses (swizzled): row m, k-granule l>>4
  const short8* aptr[4];
  const short8* bptr[4];
#pragma unroll
  for (int i = 0; i < 4; i++) {
    int m = (w >> 1) * 64 + i * 16 + (l & 15);
    int slot = m * 4 + ((l >> 4) ^ ((m >> 1) & 3));
    aptr[i] = (const short8*)&Asd[slot * 8];
    int n = (w & 1) * 64 + i * 16 + (l & 15);
    int slotb = n * 4 + ((l >> 4) ^ ((n >> 1) & 3));
    bptr[i] = (const short8*)&Bsd[slotb * 8];
  }

  floatx4 acc[4][4];
#pragma unroll
  for (int i = 0; i < 4; i++)
#pragma unroll
    for (int j = 0; j < 4; j++) acc[i][j] = (floatx4){0.f, 0.f, 0.f, 0.f};

  for (int k0 = 0; k0 < K; k0 += 32) {
    __syncthreads();
    __builtin_amdgcn_global_load_lds((const __attribute__((address_space(1))) unsigned int*)(Ag0 + k0),
                                     (__attribute__((address_space(3))) unsigned int*)ALds0, 16, 0, 0);
    __builtin_amdgcn_global_load_lds((const __attribute__((address_space(1))) unsigned int*)(Ag1 + k0),
                                     (__attribute__((address_space(3))) unsigned int*)ALds1, 16, 0, 0);
    __builtin_amdgcn_global_load_lds((const __attribute__((address_space(1))) unsigned int*)(Bg0 + k0),
                                     (__attribute__((address_space(3))) unsigned int*)BLds0, 16, 0, 0);
    __builtin_amdgcn_global_load_lds((const __attribute__((address_space(1))) unsigned int*)(Bg1 + k0),
                                     (__attribute__((address_space(3))) unsigned int*)BLds1, 16, 0, 0);
    __syncthreads();
    short8 a[4], b[4];
#pragma unroll
    for (int i = 0; i < 4; i++) a[i] = *aptr[i];
#pragma unroll
    for (int j = 0; j < 4; j++) b[j] = *bptr[j];
#pragma unroll
    for (int i = 0; i < 4; i++)
#pragma unroll
      for (int j = 0; j < 4; j++)
        acc[i][j] = __builtin_amdgcn_mfma_f32_16x16x32_bf16(a[i], b[j], acc[i][j], 0, 0, 0);
  }

#pragma unroll
  for (int i = 0; i < 4; i++) {
#pragma unroll
    for (int j = 0; j < 4; j++) {
#pragma unroll
      for (int r = 0; r < 4; r++) {
        size_t row = brow + (w >> 1) * 64 + i * 16 + (l >> 4) * 4 + r;
        size_t col = bcol + (w & 1) * 64 + j * 16 + (l & 15);
        C[row * DFF + col] = acc[i][j][r];
      }
    }
  }
}

// ---------------- top-48 per row via iterative argmax ----------------
__global__ __launch_bounds__(256) void topk_kernel(const float* __restrict__ scores,
    int* __restrict__ idxo) {
  __shared__ float sv[DFF];
  __shared__ float wrv[4];
  __shared__ int wri[4];
  int n = blockIdx.x, tid = threadIdx.x;
  const float* row = scores + (size_t)n * DFF;
  for (int i = tid; i < DFF; i += 256) sv[i] = row[i];
  __syncthreads();
  for (int it = 0; it < KCAND; it++) {
    float bv = -INFINITY;
    int bi = 0x7fffffff;
    for (int i = tid; i < DFF; i += 256) {
      float v = sv[i];
      if (v > bv) { bv = v; bi = i; }
    }
    for (int off = 32; off; off >>= 1) {
      float ov = __shfl_down(bv, off);
      int oi = __shfl_down(bi, off);
      if (ov > bv || (ov == bv && oi < bi)) { bv = ov; bi = oi; }
    }
    int wid = tid >> 6;
    if ((tid & 63) == 0) { wrv[wid] = bv; wri[wid] = bi; }
    __syncthreads();
    if (tid == 0) {
      float fv = wrv[0]; int fi = wri[0];
      for (int w = 1; w < 4; w++)
        if (wrv[w] > fv || (wrv[w] == fv && wri[w] < fi)) { fv = wrv[w]; fi = wri[w]; }
      idxo[(size_t)n * KCAND + it] = fi;
      sv[fi] = -INFINITY;
    }
    __syncthreads();
  }
}

// ---------------- fp32 rescore of 48 candidates -> exact top-32 set ----------------
__global__ __launch_bounds__(256) void rescore_kernel(const float* __restrict__ h,
    const float* __restrict__ w2f, const int* __restrict__ idx48, int* __restrict__ idx32) {
  __shared__ float sh[DM];
  __shared__ float sc[KCAND];
  __shared__ int sidx[KCAND];
  int n = blockIdx.x, tid = threadIdx.x;
  *(float4*)&sh[tid * 4] = *(const float4*)(h + (size_t)n * DM + tid * 4);
  if (tid < KCAND) sidx[tid] = idx48[(size_t)n * KCAND + tid];
  __syncthreads();
  int w = tid >> 6, lane = tid & 63;
  for (int c = w; c < KCAND; c += 4) {
    const float4* row = (const float4*)(w2f + (size_t)sidx[c] * DM);
    const float4* hp = (const float4*)sh;
    float s = 0.f;
#pragma unroll
    for (int t = 0; t < 4; t++) {
      float4 wv = row[t * 64 + lane];
      float4 hv = hp[t * 64 + lane];
      s = fmaf(wv.x, hv.x, s); s = fmaf(wv.y, hv.y, s);
      s = fmaf(wv.z, hv.z, s); s = fmaf(wv.w, hv.w, s);
    }
    for (int off = 32; off; off >>= 1) s += __shfl_xor(s, off);
    if (lane == 0) sc[c] = s;
  }
  __syncthreads();
  if (tid < KCAND) {
    float st = sc[tid]; int it = sidx[tid];
    int rank = 0;
    for (int j = 0; j < KCAND; j++) {
      float sj = sc[j];
      rank += (sj > st) || (sj == st && sidx[j] < it);
    }
    if (rank < KSEL) idx32[(size_t)n * KSEL + rank] = it;
  }
}

// ------- per-neuron qkv table -------
__global__ __launch_bounds__(384) void qkvtab_kernel(const float* __restrict__ nv,
    const float* __restrict__ ipw, const float* __restrict__ ipb, float* __restrict__ tab) {
  __shared__ float s_nv[8 * 128];
  int f0 = blockIdx.x * 8;
  int tid = threadIdx.x;
  for (int i = tid; i < 8 * 128; i += 384) s_nv[i] = nv[(size_t)f0 * 128 + i];
  __syncthreads();
  int row = tid;
  float bias = ipb[row];
  float acc[8];
#pragma unroll
  for (int ff = 0; ff < 8; ff++) acc[ff] = bias;
  const float* wr = ipw + (size_t)row * 128;
  for (int c = 0; c < 128; c++) {
    float w = wr[c];
#pragma unroll
    for (int ff = 0; ff < 8; ff++) acc[ff] = fmaf(s_nv[ff * 128 + c], w, acc[ff]);
  }
#pragma unroll
  for (int ff = 0; ff < 8; ff++) tab[(size_t)(f0 + ff) * 384 + row] = acc[ff];
}

// ---------------- fused per-token tail ----------------
#define QS 388   // qkv row stride (floats)
__global__ __launch_bounds__(256) void tail_kernel(
    const float* __restrict__ xf, const float* __restrict__ pats,
    const float* __restrict__ dirs, const float* __restrict__ qkvtab,
    const int* __restrict__ idxs,
    const float* __restrict__ opw, const float* __restrict__ opb,
    const float* __restrict__ w1, const float* __restrict__ b1,
    const float* __restrict__ w2, const float* __restrict__ b2,
    float* __restrict__ out) {
  __shared__ float s_buf[32 * QS];   // phase A: qkv[32][384]; phase B: s_at(4224) + s_w(4224)
  __shared__ float s_ao[32 * 132];
  __shared__ float s_hid[32 * 65];
  __shared__ float s_xf[1024];
  __shared__ float s_base[32];
  __shared__ float s_coef[32];
  __shared__ int s_idx[32];

  int n = blockIdx.x, tid = threadIdx.x;
  if (tid < 32) s_idx[tid] = idxs[(size_t)n * 32 + tid];
  for (int i = tid; i < 1024; i += 256) s_xf[i] = xf[(size_t)n * 1024 + i];
  __syncthreads();

  // gather qkv rows once, coalesced float4
  {
    const float4* qt4 = (const float4*)qkvtab;
#pragma unroll
    for (int p = 0; p < 12; p++) {
      int i = p * 256 + tid;
      int j = i / 96, c = i - j * 96;
      float4 v = qt4[(size_t)s_idx[j] * 96 + c];
      *(float4*)&s_buf[j * QS + c * 4] = v;
    }
  }

  // base[g] = gelu(xf . pats[idx[g]])
  {
    int g = tid >> 3, l = tid & 7;
    const float* pr = pats + (size_t)s_idx[g] * 1024;
    float s = 0.f;
    for (int c = l; c < 1024; c += 8) s = fmaf(s_xf[c], pr[c], s);
    s += __shfl_down(s, 4, 8);
    s += __shfl_down(s, 2, 8);
    s += __shfl_down(s, 1, 8);
    if (l == 0) s_base[g] = gelu_f(s);
  }
  __syncthreads();

  // attention: wave w owns heads 2w,2w+1; lane = (head-half, qj). All in registers.
  {
    int w = tid >> 6, l = tid & 63;
    int h0 = 2 * w + (l >> 5);
    int qj = l & 31;
    const float4* qr = (const float4*)&s_buf[qj * QS + h0 * 16];
    float4 q0 = qr[0], q1 = qr[1], q2 = qr[2], q3 = qr[3];
    float att[32];
#pragma unroll
    for (int kj = 0; kj < 32; kj++) {
      const float4* kr = (const float4*)&s_buf[kj * QS + 128 + h0 * 16];
      float4 k0 = kr[0], k1 = kr[1], k2 = kr[2], k3 = kr[3];
      float s = 0.f;
      s = fmaf(q0.x, k0.x, s); s = fmaf(q0.y, k0.y, s); s = fmaf(q0.z, k0.z, s); s = fmaf(q0.w, k0.w, s);
      s = fmaf(q1.x, k1.x, s); s = fmaf(q1.y, k1.y, s); s = fmaf(q1.z, k1.z, s); s = fmaf(q1.w, k1.w, s);
      s = fmaf(q2.x, k2.x, s); s = fmaf(q2.y, k2.y, s); s = fmaf(q2.z, k2.z, s); s = fmaf(q2.w, k2.w, s);
      s = fmaf(q3.x, k3.x, s); s = fmaf(q3.y, k3.y, s); s = fmaf(q3.z, k3.z, s); s = fmaf(q3.w, k3.w, s);
      att[kj] = s * 0.25f;
    }
    float m = att[0];
#pragma unroll
    for (int k = 1; k < 32; k++) m = fmaxf(m, att[k]);
    float sum = 0.f;
#pragma unroll
    for (int k = 0; k < 32; k++) { att[k] = expf(att[k] - m); sum += att[k]; }
    float inv = 1.f / sum;
#pragma unroll
    for (int k = 0; k < 32; k++) att[k] *= inv;
    float4 o0 = {0,0,0,0}, o1 = {0,0,0,0}, o2 = {0,0,0,0}, o3 = {0,0,0,0};
#pragma unroll
    for (int kj = 0; kj < 32; kj++) {
      const float4* vr = (const float4*)&s_buf[kj * QS + 256 + h0 * 16];
      float4 v0 = vr[0], v1 = vr[1], v2 = vr[2], v3 = vr[3];
      float a = att[kj];
      o0.x = fmaf(a, v0.x, o0.x); o0.y = fmaf(a, v0.y, o0.y); o0.z = fmaf(a, v0.z, o0.z); o0.w = fmaf(a, v0.w, o0.w);
      o1.x = fmaf(a, v1.x, o1.x); o1.y = fmaf(a, v1.y, o1.y); o1.z = fmaf(a, v1.z, o1.z); o1.w = fmaf(a, v1.w, o1.w);
      o2.x = fmaf(a, v2.x, o2.x); o2.y = fmaf(a, v2.y, o2.y); o2.z = fmaf(a, v2.z, o2.z); o2.w = fmaf(a, v2.w, o2.w);
      o3.x = fmaf(a, v3.x, o3.x); o3.y = fmaf(a, v3.y, o3.y); o3.z = fmaf(a, v3.z, o3.z); o3.w = fmaf(a, v3.w, o3.w);
    }
    float4* aor = (float4*)&s_ao[qj * 132 + h0 * 16];
    aor[0] = o0; aor[1] = o1; aor[2] = o2; aor[3] = o3;
  }
  __syncthreads();   // attention done: s_buf free for reuse, s_ao ready

  float* s_at = s_buf;          // 4224 floats, stride 132
  float* s_w = s_buf + 4224;    // 4224 floats

  // attended = ao @ opw^T + opb
  int tj = tid >> 5;
  int tr = tid & 31;
  {
    float acc[4][4];
#pragma unroll
    for (int i = 0; i < 4; i++)
#pragma unroll
      for (int jj = 0; jj < 4; jj++) acc[i][jj] = opb[tr + 32 * jj];
    for (int cq = 0; cq < 4; cq++) {
      for (int t = tid; t < 4096; t += 256) {
        int r = t >> 5, cc = t & 31;
        s_w[r * 33 + cc] = opw[(size_t)r * 128 + cq * 32 + cc];
      }
      __syncthreads();
#pragma unroll
      for (int cc = 0; cc < 32; cc++) {
        float a4[4], w4[4];
#pragma unroll
        for (int i = 0; i < 4; i++) a4[i] = s_ao[(tj * 4 + i) * 132 + cq * 32 + cc];
#pragma unroll
        for (int jj = 0; jj < 4; jj++) w4[jj] = s_w[(tr + 32 * jj) * 33 + cc];
#pragma unroll
        for (int i = 0; i < 4; i++)
#pragma unroll
          for (int jj = 0; jj < 4; jj++) acc[i][jj] = fmaf(a4[i], w4[jj], acc[i][jj]);
      }
      __syncthreads();
    }
#pragma unroll
    for (int i = 0; i < 4; i++)
#pragma unroll
      for (int jj = 0; jj < 4; jj++)
        s_at[(tj * 4 + i) * 132 + tr + 32 * jj] = acc[i][jj];
  }
  __syncthreads();

  // gate hidden
  for (int half = 0; half < 2; half++) {
    for (int t = tid; t < 4096; t += 256) {
      int r = t >> 7, c = t & 127;
      s_w[r * 129 + c] = w1[(size_t)(half * 32 + r) * 128 + c];
    }
    __syncthreads();
    float a4[4];
    float bb = b1[half * 32 + tr];
#pragma unroll
    for (int i = 0; i < 4; i++) a4[i] = bb;
    for (int c = 0; c < 128; c++) {
      float w = s_w[tr * 129 + c];
#pragma unroll
      for (int i = 0; i < 4; i++) a4[i] = fmaf(s_at[(tj * 4 + i) * 132 + c], w, a4[i]);
    }
#pragma unroll
    for (int i = 0; i < 4; i++)
      s_hid[(tj * 4 + i) * 65 + half * 32 + tr] = gelu_f(a4[i]);
    __syncthreads();
  }

  if (tid < 32) {
    float a = b2[0];
    for (int r = 0; r < 64; r++) a = fmaf(s_hid[tid * 65 + r], w2[r], a);
    float sw = 1.f / (1.f + expf(-a));
    s_coef[tid] = s_base[tid] * sw;
  }
  __syncthreads();

#pragma unroll
  for (int p = 0; p < 4; p++) {
    int d = tid + p * 256;
    float a = 0.f;
    for (int j = 0; j < 32; j++)
      a = fmaf(s_coef[j], dirs[(size_t)s_idx[j] * 1024 + d], a);
    out[(size_t)n * 1024 + d] = a;
  }
}

extern "C" void kernel_launch(void* const* d_in, const int* in_sizes, int n_in,
                              void* d_out, int out_size, void* d_ws, size_t ws_size,
                              hipStream_t stream) {
  const float* x    = (const float*)d_in[0];
  const float* pats = (const float*)d_in[1];
  const float* nv   = (const float*)d_in[2];
  const float* dirs = (const float*)d_in[3];
  const float* rw1  = (const float*)d_in[4];
  const float* rw2  = (const float*)d_in[5];
  const float* lng  = (const float*)d_in[6];
  const float* lnb  = (const float*)d_in[7];
  const float* ipw  = (const float*)d_in[8];
  const float* ipb  = (const float*)d_in[9];
  const float* opw  = (const float*)d_in[10];
  const float* opb  = (const float*)d_in[11];
  const float* w1   = (const float*)d_in[12];
  const float* b1   = (const float*)d_in[13];
  const float* w2   = (const float*)d_in[14];
  const float* b2   = (const float*)d_in[15];
  float* out = (float*)d_out;

  // workspace: xn | h | scores | qtab | hb | w2b | idx48 | idx32  (~125 MB)
  float* xn     = (float*)d_ws;
  float* h      = xn + (size_t)N_TOK * DM;
  float* scores = h + (size_t)N_TOK * DM;
  float* qtab   = scores + (size_t)N_TOK * DFF;
  __hip_bfloat16* hb  = (__hip_bfloat16*)(qtab + (size_t)DFF * 384);
  __hip_bfloat16* w2b = hb + (size_t)N_TOK * DM;
  int* idx48 = (int*)(w2b + (size_t)DFF * DM);
  int* idx32 = idx48 + (size_t)N_TOK * KCAND;

  ln_kernel<<<N_TOK, 256, 0, stream>>>(x, lng, lnb, xn);
  gemm_nt<<<dim3(DM / 128, N_TOK / 128), 256, 0, stream>>>(xn, rw1, h, hb, N_TOK, DM, DM, 1);
  cvt_bf16<<<(DFF * DM) / 1024, 256, 0, stream>>>(rw2, w2b, DFF * DM / 4);
  gemm_bf<<<dim3(DFF / 128, N_TOK / 128), 256, 0, stream>>>(hb, w2b, scores);
  topk_kernel<<<N_TOK, 256, 0, stream>>>(scores, idx48);
  rescore_kernel<<<N_TOK, 256, 0, stream>>>(h, rw2, idx48, idx32);
  qkvtab_kernel<<<DFF / 8, 384, 0, stream>>>(nv, ipw, ipb, qtab);
  tail_kernel<<<N_TOK, 256, 0, stream>>>(x, pats, dirs, qtab, idx32,
                                         opw, opb, w1, b1, w2, b2, out);
}

// Round 3
// 916.132 us; speedup vs baseline: 2.0617x; 1.3261x over previous
//
#include <hip/hip_runtime.h>
#include <math.h>

#define N_TOK 4096
#define DM 1024
#define DFF 4096
#define DN 128
#define NH 8
#define HD 16
#define KSEL 32
#define KCAND 48

typedef __attribute__((ext_vector_type(4))) float floatx4;
typedef __attribute__((ext_vector_type(8))) short short8;
typedef __attribute__((ext_vector_type(8))) unsigned short ushort8v;
typedef __attribute__((ext_vector_type(4))) unsigned short ushort4v;

__device__ __forceinline__ float gelu_f(float x) {
  return 0.5f * x * (1.0f + erff(x * 0.70710678118654752440f));
}
__device__ __forceinline__ float bf2f(unsigned short u) {
  union { unsigned int i; float f; } v; v.i = ((unsigned int)u) << 16; return v.f;
}
__device__ __forceinline__ unsigned short f2bf(float f) {
  unsigned int x = __float_as_uint(f);
  unsigned int r = (x + 0x7fffu + ((x >> 16) & 1u)) >> 16;
  return (unsigned short)r;
}

// ---------------- LayerNorm ----------------
__global__ __launch_bounds__(256) void ln_kernel(const float* __restrict__ x,
    const float* __restrict__ g, const float* __restrict__ b, float* __restrict__ xn) {
  int n = blockIdx.x, tid = threadIdx.x;
  const float* row = x + (size_t)n * DM;
  float s = 0.f, sq = 0.f;
  for (int i = tid; i < DM; i += 256) { float v = row[i]; s += v; sq += v * v; }
  for (int off = 32; off; off >>= 1) { s += __shfl_down(s, off); sq += __shfl_down(sq, off); }
  __shared__ float ss[4], ssq[4];
  __shared__ float s_mu, s_rs;
  int wid = tid >> 6;
  if ((tid & 63) == 0) { ss[wid] = s; ssq[wid] = sq; }
  __syncthreads();
  if (tid == 0) {
    float S = ss[0] + ss[1] + ss[2] + ss[3];
    float Q = ssq[0] + ssq[1] + ssq[2] + ssq[3];
    float mu = S * (1.f / DM);
    float var = Q * (1.f / DM) - mu * mu;
    s_mu = mu; s_rs = rsqrtf(var + 1e-5f);
  }
  __syncthreads();
  float mu = s_mu, rs = s_rs;
  float* o = xn + (size_t)n * DM;
  for (int i = tid; i < DM; i += 256) o[i] = (row[i] - mu) * rs * g[i] + b[i];
}

// ---------------- fp32 GEMM (gemm1): C = gelu(A@B^T), emits bf16 copy ----------------
// Conflict-free micro-tile: row = i*16+ty, col = j*16+tx.
__global__ __launch_bounds__(256) void gemm_nt(const float* __restrict__ A,
    const float* __restrict__ B, float* __restrict__ C, unsigned short* __restrict__ Cb,
    int M, int N, int K) {
  __shared__ float As[128 * 33];
  __shared__ float Bs[128 * 33];
  int tid = threadIdx.x;
  int tx = tid & 15, ty = tid >> 4;
  const float* Ab = A + (size_t)blockIdx.y * 128 * K;
  const float* Bb = B + (size_t)blockIdx.x * 128 * K;
  float acc[8][8] = {};
  for (int k0 = 0; k0 < K; k0 += 32) {
#pragma unroll
    for (int i = 0; i < 16; i++) {
      int l = tid + i * 256;
      int r = l >> 5, c = l & 31;
      As[r * 33 + c] = Ab[(size_t)r * K + k0 + c];
      Bs[r * 33 + c] = Bb[(size_t)r * K + k0 + c];
    }
    __syncthreads();
#pragma unroll
    for (int kk = 0; kk < 32; kk++) {
      float a[8], b[8];
#pragma unroll
      for (int i = 0; i < 8; i++) a[i] = As[(i * 16 + ty) * 33 + kk];
#pragma unroll
      for (int j = 0; j < 8; j++) b[j] = Bs[(j * 16 + tx) * 33 + kk];
#pragma unroll
      for (int i = 0; i < 8; i++)
#pragma unroll
        for (int j = 0; j < 8; j++)
          acc[i][j] = fmaf(a[i], b[j], acc[i][j]);
    }
    __syncthreads();
  }
#pragma unroll
  for (int i = 0; i < 8; i++) {
    size_t m = (size_t)blockIdx.y * 128 + i * 16 + ty;
#pragma unroll
    for (int j = 0; j < 8; j++) {
      size_t col = (size_t)blockIdx.x * 128 + j * 16 + tx;
      float v = gelu_f(acc[i][j]);
      C[m * N + col] = v;
      Cb[m * N + col] = f2bf(v);
    }
  }
}

// ---------------- generic fp32 -> bf16 convert ----------------
__global__ __launch_bounds__(256) void cvt_bf16(const float* __restrict__ in,
    unsigned short* __restrict__ out) {
  int i = (blockIdx.x * 256 + threadIdx.x) * 4;
  float4 v = *(const float4*)(in + i);
  ushort4v o = {f2bf(v.x), f2bf(v.y), f2bf(v.z), f2bf(v.w)};
  *(ushort4v*)(out + i) = o;
}

// ---------------- bf16 MFMA GEMM: scores_approx(bf16) = hb @ w2b^T ----------------
__global__ __launch_bounds__(256) void gemm_bf(const unsigned short* __restrict__ Ah,
    const unsigned short* __restrict__ Bh, unsigned short* __restrict__ C) {
  __shared__ short Asd[128 * 32];
  __shared__ short Bsd[128 * 32];
  const int K = 1024;
  int tid = threadIdx.x;
  int w = tid >> 6, l = tid & 63;
  size_t brow = (size_t)blockIdx.y * 128;
  size_t bcol = (size_t)blockIdx.x * 128;
  const short* Ab = (const short*)Ah + brow * K;
  const short* Bb = (const short*)Bh + bcol * K;

  int r0 = w * 32 + (l >> 2);
  int g0 = (l & 3) ^ ((r0 >> 1) & 3);
  const short* Ag0 = Ab + (size_t)r0 * K + g0 * 8;
  const short* Ag1 = Ab + (size_t)(r0 + 16) * K + g0 * 8;
  const short* Bg0 = Bb + (size_t)r0 * K + g0 * 8;
  const short* Bg1 = Bb + (size_t)(r0 + 16) * K + g0 * 8;
  short* ALds0 = &Asd[w * 1024];
  short* ALds1 = &Asd[w * 1024 + 512];
  short* BLds0 = &Bsd[w * 1024];
  short* BLds1 = &Bsd[w * 1024 + 512];

  const short8* aptr[4];
  const short8* bptr[4];
#pragma unroll
  for (int i = 0; i < 4; i++) {
    int m = (w >> 1) * 64 + i * 16 + (l & 15);
    int slot = m * 4 + ((l >> 4) ^ ((m >> 1) & 3));
    aptr[i] = (const short8*)&Asd[slot * 8];
    int n = (w & 1) * 64 + i * 16 + (l & 15);
    int slotb = n * 4 + ((l >> 4) ^ ((n >> 1) & 3));
    bptr[i] = (const short8*)&Bsd[slotb * 8];
  }

  floatx4 acc[4][4];
#pragma unroll
  for (int i = 0; i < 4; i++)
#pragma unroll
    for (int j = 0; j < 4; j++) acc[i][j] = (floatx4){0.f, 0.f, 0.f, 0.f};

  for (int k0 = 0; k0 < K; k0 += 32) {
    __syncthreads();
    __builtin_amdgcn_global_load_lds((const __attribute__((address_space(1))) unsigned int*)(Ag0 + k0),
                                     (__attribute__((address_space(3))) unsigned int*)ALds0, 16, 0, 0);
    __builtin_amdgcn_global_load_lds((const __attribute__((address_space(1))) unsigned int*)(Ag1 + k0),
                                     (__attribute__((address_space(3))) unsigned int*)ALds1, 16, 0, 0);
    __builtin_amdgcn_global_load_lds((const __attribute__((address_space(1))) unsigned int*)(Bg0 + k0),
                                     (__attribute__((address_space(3))) unsigned int*)BLds0, 16, 0, 0);
    __builtin_amdgcn_global_load_lds((const __attribute__((address_space(1))) unsigned int*)(Bg1 + k0),
                                     (__attribute__((address_space(3))) unsigned int*)BLds1, 16, 0, 0);
    __syncthreads();
    short8 a[4], b[4];
#pragma unroll
    for (int i = 0; i < 4; i++) a[i] = *aptr[i];
#pragma unroll
    for (int j = 0; j < 4; j++) b[j] = *bptr[j];
#pragma unroll
    for (int i = 0; i < 4; i++)
#pragma unroll
      for (int j = 0; j < 4; j++)
        acc[i][j] = __builtin_amdgcn_mfma_f32_16x16x32_bf16(a[i], b[j], acc[i][j], 0, 0, 0);
  }

#pragma unroll
  for (int i = 0; i < 4; i++) {
#pragma unroll
    for (int j = 0; j < 4; j++) {
#pragma unroll
      for (int r = 0; r < 4; r++) {
        size_t row = brow + (w >> 1) * 64 + i * 16 + (l >> 4) * 4 + r;
        size_t col = bcol + (w & 1) * 64 + j * 16 + (l & 15);
        C[row * DFF + col] = f2bf(acc[i][j][r]);
      }
    }
  }
}

// ---------------- top-48 per row (bf16 scores) via iterative argmax ----------------
__global__ __launch_bounds__(256) void topk_kernel(const unsigned short* __restrict__ scores,
    int* __restrict__ idxo) {
  __shared__ float sv[DFF];
  __shared__ float wrv[4];
  __shared__ int wri[4];
  int n = blockIdx.x, tid = threadIdx.x;
  const unsigned short* row = scores + (size_t)n * DFF;
  for (int i = tid; i < DFF; i += 256) sv[i] = bf2f(row[i]);
  __syncthreads();
  for (int it = 0; it < KCAND; it++) {
    float bv = -INFINITY;
    int bi = 0x7fffffff;
    for (int i = tid; i < DFF; i += 256) {
      float v = sv[i];
      if (v > bv) { bv = v; bi = i; }
    }
    for (int off = 32; off; off >>= 1) {
      float ov = __shfl_down(bv, off);
      int oi = __shfl_down(bi, off);
      if (ov > bv || (ov == bv && oi < bi)) { bv = ov; bi = oi; }
    }
    int wid = tid >> 6;
    if ((tid & 63) == 0) { wrv[wid] = bv; wri[wid] = bi; }
    __syncthreads();
    if (tid == 0) {
      float fv = wrv[0]; int fi = wri[0];
      for (int w = 1; w < 4; w++)
        if (wrv[w] > fv || (wrv[w] == fv && wri[w] < fi)) { fv = wrv[w]; fi = wri[w]; }
      idxo[(size_t)n * KCAND + it] = fi;
      sv[fi] = -INFINITY;
    }
    __syncthreads();
  }
}

// ---------------- fp32 rescore of 48 candidates -> exact top-32 set ----------------
__global__ __launch_bounds__(256) void rescore_kernel(const float* __restrict__ h,
    const float* __restrict__ w2f, const int* __restrict__ idx48, int* __restrict__ idx32) {
  __shared__ float sh[DM];
  __shared__ float sc[KCAND];
  __shared__ int sidx[KCAND];
  int n = blockIdx.x, tid = threadIdx.x;
  *(float4*)&sh[tid * 4] = *(const float4*)(h + (size_t)n * DM + tid * 4);
  if (tid < KCAND) sidx[tid] = idx48[(size_t)n * KCAND + tid];
  __syncthreads();
  int w = tid >> 6, lane = tid & 63;
  for (int c = w; c < KCAND; c += 4) {
    const float4* row = (const float4*)(w2f + (size_t)sidx[c] * DM);
    const float4* hp = (const float4*)sh;
    float s = 0.f;
#pragma unroll
    for (int t = 0; t < 4; t++) {
      float4 wv = row[t * 64 + lane];
      float4 hv = hp[t * 64 + lane];
      s = fmaf(wv.x, hv.x, s); s = fmaf(wv.y, hv.y, s);
      s = fmaf(wv.z, hv.z, s); s = fmaf(wv.w, hv.w, s);
    }
    for (int off = 32; off; off >>= 1) s += __shfl_xor(s, off);
    if (lane == 0) sc[c] = s;
  }
  __syncthreads();
  if (tid < KCAND) {
    float st = sc[tid]; int it = sidx[tid];
    int rank = 0;
    for (int j = 0; j < KCAND; j++) {
      float sj = sc[j];
      rank += (sj > st) || (sj == st && sidx[j] < it);
    }
    if (rank < KSEL) idx32[(size_t)n * KSEL + rank] = it;
  }
}

// ------- per-neuron qkv table (bf16 out) -------
__global__ __launch_bounds__(384) void qkvtab_kernel(const float* __restrict__ nv,
    const float* __restrict__ ipw, const float* __restrict__ ipb,
    unsigned short* __restrict__ tab) {
  __shared__ float s_nv[8 * 128];
  int f0 = blockIdx.x * 8;
  int tid = threadIdx.x;
  for (int i = tid; i < 8 * 128; i += 384) s_nv[i] = nv[(size_t)f0 * 128 + i];
  __syncthreads();
  int row = tid;
  float bias = ipb[row];
  float acc[8];
#pragma unroll
  for (int ff = 0; ff < 8; ff++) acc[ff] = bias;
  const float* wr = ipw + (size_t)row * 128;
  for (int c = 0; c < 128; c++) {
    float w = wr[c];
#pragma unroll
    for (int ff = 0; ff < 8; ff++) acc[ff] = fmaf(s_nv[ff * 128 + c], w, acc[ff]);
  }
#pragma unroll
  for (int ff = 0; ff < 8; ff++) tab[(size_t)(f0 + ff) * 384 + row] = f2bf(acc[ff]);
}

// ---------------- fused per-token tail v2: 2 tokens/block, MFMA out_proj+gate ----------------
#define AOS 136   // LDS row stride (ushorts) for ao / attended
__global__ __launch_bounds__(256) void tail2_kernel(
    const float* __restrict__ xf, const unsigned short* __restrict__ pats_b,
    const unsigned short* __restrict__ dirs_b, const unsigned short* __restrict__ qtab_b,
    const int* __restrict__ idxs,
    const unsigned short* __restrict__ opwb, const float* __restrict__ opb,
    const unsigned short* __restrict__ w1b, const float* __restrict__ b1,
    const float* __restrict__ w2, const float* __restrict__ b2,
    float* __restrict__ out) {
  __shared__ float s_xf[2][1024];
  __shared__ unsigned short s_ao[64 * AOS];
  __shared__ unsigned short s_at[64 * AOS];
  __shared__ float s_base[64];
  __shared__ float s_coef[64];
  __shared__ int s_idx[64];

  int n0 = blockIdx.x * 2;
  int tid = threadIdx.x;
  int w = tid >> 6, l = tid & 63;

  if (tid < 64) s_idx[tid] = idxs[(size_t)n0 * 32 + tid];
#pragma unroll
  for (int t = 0; t < 2; t++)
    for (int i = tid; i < 1024; i += 256)
      s_xf[t][i] = xf[(size_t)(n0 + t) * 1024 + i];
  __syncthreads();

  // ---- base[t][j] = gelu(xf . pats[idx]) : (t,j,lq) = (tid>>7, (tid>>2)&31, tid&3)
  {
    int t = tid >> 7, j = (tid >> 2) & 31, lq = tid & 3;
    const ushort8v* pr = (const ushort8v*)(pats_b + (size_t)s_idx[t * 32 + j] * 1024);
    const float* xr = s_xf[t];
    float s = 0.f;
#pragma unroll 8
    for (int it = 0; it < 32; it++) {
      int g = it * 4 + lq;
      ushort8v pv = pr[g];
#pragma unroll
      for (int e = 0; e < 8; e++) s = fmaf(bf2f(pv[e]), xr[g * 8 + e], s);
    }
    s += __shfl_xor(s, 1);
    s += __shfl_xor(s, 2);
    if (lq == 0) s_base[t * 32 + j] = gelu_f(s);
  }

  // ---- attention: wave w -> token w>>1, head-quad w&1; 2 passes x 2 lane-half heads
  {
    int t = w >> 1, hq = w & 1, qj = l & 31;
    const int* myidx = &s_idx[t * 32];
#pragma unroll
    for (int p = 0; p < 2; p++) {
      int h0 = hq * 4 + p * 2 + (l >> 5);
      const ushort8v* qr = (const ushort8v*)(qtab_b + (size_t)myidx[qj] * 384 + h0 * 16);
      ushort8v q0 = qr[0], q1 = qr[1];
      float q[16];
#pragma unroll
      for (int e = 0; e < 8; e++) { q[e] = bf2f(q0[e]); q[8 + e] = bf2f(q1[e]); }
      float att[32];
#pragma unroll 8
      for (int kj = 0; kj < 32; kj++) {
        const ushort8v* kr = (const ushort8v*)(qtab_b + (size_t)myidx[kj] * 384 + 128 + h0 * 16);
        ushort8v k0 = kr[0], k1 = kr[1];
        float s = 0.f;
#pragma unroll
        for (int e = 0; e < 8; e++) s = fmaf(q[e], bf2f(k0[e]), s);
#pragma unroll
        for (int e = 0; e < 8; e++) s = fmaf(q[8 + e], bf2f(k1[e]), s);
        att[kj] = s * 0.25f;
      }
      float m = att[0];
#pragma unroll
      for (int k = 1; k < 32; k++) m = fmaxf(m, att[k]);
      float sum = 0.f;
#pragma unroll
      for (int k = 0; k < 32; k++) { att[k] = expf(att[k] - m); sum += att[k]; }
      float inv = 1.f / sum;
#pragma unroll
      for (int k = 0; k < 32; k++) att[k] *= inv;
      float o[16];
#pragma unroll
      for (int e = 0; e < 16; e++) o[e] = 0.f;
#pragma unroll 8
      for (int kj = 0; kj < 32; kj++) {
        const ushort8v* vr = (const ushort8v*)(qtab_b + (size_t)myidx[kj] * 384 + 256 + h0 * 16);
        ushort8v v0 = vr[0], v1 = vr[1];
        float a = att[kj];
#pragma unroll
        for (int e = 0; e < 8; e++) o[e] = fmaf(a, bf2f(v0[e]), o[e]);
#pragma unroll
        for (int e = 0; e < 8; e++) o[8 + e] = fmaf(a, bf2f(v1[e]), o[8 + e]);
      }
      ushort8v o0, o1;
#pragma unroll
      for (int e = 0; e < 8; e++) { o0[e] = f2bf(o[e]); o1[e] = f2bf(o[8 + e]); }
      ushort8v* ao = (ushort8v*)&s_ao[(t * 32 + qj) * AOS + h0 * 16];
      ao[0] = o0; ao[1] = o1;
    }
  }
  __syncthreads();

  // ---- out_proj MFMA: attended[64][128] = ao @ opwb^T + opb ; wave w -> m-tile w
  {
    floatx4 acc[8];
#pragma unroll
    for (int nt = 0; nt < 8; nt++) acc[nt] = (floatx4){0.f, 0.f, 0.f, 0.f};
#pragma unroll
    for (int kst = 0; kst < 4; kst++) {
      short8 a = *(const short8*)&s_ao[(w * 16 + (l & 15)) * AOS + kst * 32 + (l >> 4) * 8];
#pragma unroll
      for (int nt = 0; nt < 8; nt++) {
        short8 b = *(const short8*)&opwb[(size_t)(nt * 16 + (l & 15)) * 128 + kst * 32 + (l >> 4) * 8];
        acc[nt] = __builtin_amdgcn_mfma_f32_16x16x32_bf16(a, b, acc[nt], 0, 0, 0);
      }
    }
#pragma unroll
    for (int nt = 0; nt < 8; nt++) {
      int col = nt * 16 + (l & 15);
      float bias = opb[col];
#pragma unroll
      for (int r = 0; r < 4; r++) {
        int row = w * 16 + (l >> 4) * 4 + r;
        s_at[row * AOS + col] = f2bf(acc[nt][r] + bias);
      }
    }
  }
  __syncthreads();

  // ---- gate MFMA: hid[64][64] = gelu(attended @ w1b^T + b1); logit reduce in-reg
  {
    floatx4 acc[4];
#pragma unroll
    for (int nt = 0; nt < 4; nt++) acc[nt] = (floatx4){0.f, 0.f, 0.f, 0.f};
#pragma unroll
    for (int kst = 0; kst < 4; kst++) {
      short8 a = *(const short8*)&s_at[(w * 16 + (l & 15)) * AOS + kst * 32 + (l >> 4) * 8];
#pragma unroll
      for (int nt = 0; nt < 4; nt++) {
        short8 b = *(const short8*)&w1b[(size_t)(nt * 16 + (l & 15)) * 128 + kst * 32 + (l >> 4) * 8];
        acc[nt] = __builtin_amdgcn_mfma_f32_16x16x32_bf16(a, b, acc[nt], 0, 0, 0);
      }
    }
    float p[4] = {0.f, 0.f, 0.f, 0.f};
#pragma unroll
    for (int nt = 0; nt < 4; nt++) {
      int col = nt * 16 + (l & 15);
      float bb = b1[col], ww = w2[col];
#pragma unroll
      for (int r = 0; r < 4; r++)
        p[r] = fmaf(gelu_f(acc[nt][r] + bb), ww, p[r]);
    }
#pragma unroll
    for (int r = 0; r < 4; r++) {
      p[r] += __shfl_xor(p[r], 1);
      p[r] += __shfl_xor(p[r], 2);
      p[r] += __shfl_xor(p[r], 4);
      p[r] += __shfl_xor(p[r], 8);
    }
    if ((l & 15) == 0) {
      float b2v = b2[0];
#pragma unroll
      for (int r = 0; r < 4; r++) {
        int row = w * 16 + (l >> 4) * 4 + r;
        float sw = 1.f / (1.f + expf(-(p[r] + b2v)));
        s_coef[row] = s_base[row] * sw;
      }
    }
  }
  __syncthreads();

  // ---- output: out[t][d] = sum_j coef * dirs_b[idx[j]][d]
#pragma unroll
  for (int t = 0; t < 2; t++) {
    int d0 = tid * 4;
    float4 a = {0.f, 0.f, 0.f, 0.f};
#pragma unroll 8
    for (int j = 0; j < 32; j++) {
      float c = s_coef[t * 32 + j];
      ushort4v dv = *(const ushort4v*)&dirs_b[(size_t)s_idx[t * 32 + j] * 1024 + d0];
      a.x = fmaf(c, bf2f(dv.x), a.x);
      a.y = fmaf(c, bf2f(dv.y), a.y);
      a.z = fmaf(c, bf2f(dv.z), a.z);
      a.w = fmaf(c, bf2f(dv.w), a.w);
    }
    *(float4*)&out[(size_t)(n0 + t) * 1024 + d0] = a;
  }
}

extern "C" void kernel_launch(void* const* d_in, const int* in_sizes, int n_in,
                              void* d_out, int out_size, void* d_ws, size_t ws_size,
                              hipStream_t stream) {
  const float* x    = (const float*)d_in[0];
  const float* pats = (const float*)d_in[1];
  const float* nv   = (const float*)d_in[2];
  const float* dirs = (const float*)d_in[3];
  const float* rw1  = (const float*)d_in[4];
  const float* rw2  = (const float*)d_in[5];
  const float* lng  = (const float*)d_in[6];
  const float* lnb  = (const float*)d_in[7];
  const float* ipw  = (const float*)d_in[8];
  const float* ipb  = (const float*)d_in[9];
  const float* opw  = (const float*)d_in[10];
  const float* opb  = (const float*)d_in[11];
  const float* w1   = (const float*)d_in[12];
  const float* b1   = (const float*)d_in[13];
  const float* w2   = (const float*)d_in[14];
  const float* b2   = (const float*)d_in[15];
  float* out = (float*)d_out;

  const size_t MB = 1u << 20;
  char* ws = (char*)d_ws;
  float* xn            = (float*)(ws + 0);            // 16 MB
  float* h             = (float*)(ws + 16 * MB);      // 16 MB
  unsigned short* sb   = (unsigned short*)(ws + 32 * MB);  // 32 MB (bf16 scores)
  unsigned short* qtab = (unsigned short*)(ws + 64 * MB);  // 3 MB
  unsigned short* hb   = (unsigned short*)(ws + 67 * MB);  // 8 MB
  unsigned short* w2b  = (unsigned short*)(ws + 75 * MB);  // 8 MB
  unsigned short* patsb= (unsigned short*)(ws + 83 * MB);  // 8 MB
  unsigned short* dirsb= (unsigned short*)(ws + 91 * MB);  // 8 MB
  unsigned short* opwb = (unsigned short*)(ws + 99 * MB);  // 32 KB
  unsigned short* w1b  = (unsigned short*)(ws + 99 * MB + 64 * 1024);  // 16 KB
  int* idx48           = (int*)(ws + 99 * MB + 128 * 1024);            // 768 KB
  int* idx32           = (int*)(ws + 100 * MB);                        // 512 KB

  ln_kernel<<<N_TOK, 256, 0, stream>>>(x, lng, lnb, xn);
  gemm_nt<<<dim3(DM / 128, N_TOK / 128), 256, 0, stream>>>(xn, rw1, h, hb, N_TOK, DM, DM);
  cvt_bf16<<<(DFF * DM) / 1024, 256, 0, stream>>>(rw2, w2b);
  cvt_bf16<<<(DFF * DM) / 1024, 256, 0, stream>>>(pats, patsb);
  cvt_bf16<<<(DFF * DM) / 1024, 256, 0, stream>>>(dirs, dirsb);
  cvt_bf16<<<(DN * DN) / 1024, 256, 0, stream>>>(opw, opwb);
  cvt_bf16<<<(DN * DN / 2) / 1024, 256, 0, stream>>>(w1, w1b);
  gemm_bf<<<dim3(DFF / 128, N_TOK / 128), 256, 0, stream>>>(hb, w2b, sb);
  topk_kernel<<<N_TOK, 256, 0, stream>>>(sb, idx48);
  rescore_kernel<<<N_TOK, 256, 0, stream>>>(h, rw2, idx48, idx32);
  qkvtab_kernel<<<DFF / 8, 384, 0, stream>>>(nv, ipw, ipb, qtab);
  tail2_kernel<<<N_TOK / 2, 256, 0, stream>>>(x, patsb, dirsb, qtab, idx32,
                                              opwb, opb, w1b, b1, w2, b2, out);
}

// Round 4
// 693.352 us; speedup vs baseline: 2.7242x; 1.3213x over previous
//
#include <hip/hip_runtime.h>
#include <math.h>

#define N_TOK 4096
#define DM 1024
#define DFF 4096
#define DN 128
#define NH 8
#define HD 16
#define KSEL 32
#define KCAND 48
#define KMAX 64

typedef __attribute__((ext_vector_type(4))) float floatx4;
typedef __attribute__((ext_vector_type(8))) short short8;
typedef __attribute__((ext_vector_type(8))) unsigned short ushort8v;
typedef __attribute__((ext_vector_type(4))) unsigned short ushort4v;

__device__ __forceinline__ float gelu_f(float x) {
  return 0.5f * x * (1.0f + erff(x * 0.70710678118654752440f));
}
__device__ __forceinline__ float bf2f(unsigned short u) {
  union { unsigned int i; float f; } v; v.i = ((unsigned int)u) << 16; return v.f;
}
__device__ __forceinline__ unsigned short f2bf(float f) {
  unsigned int x = __float_as_uint(f);
  unsigned int r = (x + 0x7fffu + ((x >> 16) & 1u)) >> 16;
  return (unsigned short)r;
}

// ---------------- LayerNorm ----------------
__global__ __launch_bounds__(256) void ln_kernel(const float* __restrict__ x,
    const float* __restrict__ g, const float* __restrict__ b, float* __restrict__ xn) {
  int n = blockIdx.x, tid = threadIdx.x;
  const float* row = x + (size_t)n * DM;
  float s = 0.f, sq = 0.f;
  for (int i = tid; i < DM; i += 256) { float v = row[i]; s += v; sq += v * v; }
  for (int off = 32; off; off >>= 1) { s += __shfl_down(s, off); sq += __shfl_down(sq, off); }
  __shared__ float ss[4], ssq[4];
  __shared__ float s_mu, s_rs;
  int wid = tid >> 6;
  if ((tid & 63) == 0) { ss[wid] = s; ssq[wid] = sq; }
  __syncthreads();
  if (tid == 0) {
    float S = ss[0] + ss[1] + ss[2] + ss[3];
    float Q = ssq[0] + ssq[1] + ssq[2] + ssq[3];
    float mu = S * (1.f / DM);
    float var = Q * (1.f / DM) - mu * mu;
    s_mu = mu; s_rs = rsqrtf(var + 1e-5f);
  }
  __syncthreads();
  float mu = s_mu, rs = s_rs;
  float* o = xn + (size_t)n * DM;
  for (int i = tid; i < DM; i += 256) o[i] = (row[i] - mu) * rs * g[i] + b[i];
}

// ---------------- fp32 GEMM (gemm1): C = gelu(A@B^T), emits bf16 copy ----------------
__global__ __launch_bounds__(256) void gemm_nt(const float* __restrict__ A,
    const float* __restrict__ B, float* __restrict__ C, unsigned short* __restrict__ Cb,
    int M, int N, int K) {
  __shared__ float As[128 * 33];
  __shared__ float Bs[128 * 33];
  int tid = threadIdx.x;
  int tx = tid & 15, ty = tid >> 4;
  const float* Ab = A + (size_t)blockIdx.y * 128 * K;
  const float* Bb = B + (size_t)blockIdx.x * 128 * K;
  float acc[8][8] = {};
  for (int k0 = 0; k0 < K; k0 += 32) {
#pragma unroll
    for (int i = 0; i < 16; i++) {
      int l = tid + i * 256;
      int r = l >> 5, c = l & 31;
      As[r * 33 + c] = Ab[(size_t)r * K + k0 + c];
      Bs[r * 33 + c] = Bb[(size_t)r * K + k0 + c];
    }
    __syncthreads();
#pragma unroll
    for (int kk = 0; kk < 32; kk++) {
      float a[8], b[8];
#pragma unroll
      for (int i = 0; i < 8; i++) a[i] = As[(i * 16 + ty) * 33 + kk];
#pragma unroll
      for (int j = 0; j < 8; j++) b[j] = Bs[(j * 16 + tx) * 33 + kk];
#pragma unroll
      for (int i = 0; i < 8; i++)
#pragma unroll
        for (int j = 0; j < 8; j++)
          acc[i][j] = fmaf(a[i], b[j], acc[i][j]);
    }
    __syncthreads();
  }
#pragma unroll
  for (int i = 0; i < 8; i++) {
    size_t m = (size_t)blockIdx.y * 128 + i * 16 + ty;
#pragma unroll
    for (int j = 0; j < 8; j++) {
      size_t col = (size_t)blockIdx.x * 128 + j * 16 + tx;
      float v = gelu_f(acc[i][j]);
      C[m * N + col] = v;
      Cb[m * N + col] = f2bf(v);
    }
  }
}

// ---------------- generic fp32 -> bf16 convert ----------------
__global__ __launch_bounds__(256) void cvt_bf16(const float* __restrict__ in,
    unsigned short* __restrict__ out) {
  int i = (blockIdx.x * 256 + threadIdx.x) * 4;
  float4 v = *(const float4*)(in + i);
  ushort4v o = {f2bf(v.x), f2bf(v.y), f2bf(v.z), f2bf(v.w)};
  *(ushort4v*)(out + i) = o;
}

// ---------------- bf16 MFMA GEMM: scores_approx(bf16) = hb @ w2b^T ----------------
__global__ __launch_bounds__(256) void gemm_bf(const unsigned short* __restrict__ Ah,
    const unsigned short* __restrict__ Bh, unsigned short* __restrict__ C) {
  __shared__ short Asd[128 * 32];
  __shared__ short Bsd[128 * 32];
  const int K = 1024;
  int tid = threadIdx.x;
  int w = tid >> 6, l = tid & 63;
  size_t brow = (size_t)blockIdx.y * 128;
  size_t bcol = (size_t)blockIdx.x * 128;
  const short* Ab = (const short*)Ah + brow * K;
  const short* Bb = (const short*)Bh + bcol * K;

  int r0 = w * 32 + (l >> 2);
  int g0 = (l & 3) ^ ((r0 >> 1) & 3);
  const short* Ag0 = Ab + (size_t)r0 * K + g0 * 8;
  const short* Ag1 = Ab + (size_t)(r0 + 16) * K + g0 * 8;
  const short* Bg0 = Bb + (size_t)r0 * K + g0 * 8;
  const short* Bg1 = Bb + (size_t)(r0 + 16) * K + g0 * 8;
  short* ALds0 = &Asd[w * 1024];
  short* ALds1 = &Asd[w * 1024 + 512];
  short* BLds0 = &Bsd[w * 1024];
  short* BLds1 = &Bsd[w * 1024 + 512];

  const short8* aptr[4];
  const short8* bptr[4];
#pragma unroll
  for (int i = 0; i < 4; i++) {
    int m = (w >> 1) * 64 + i * 16 + (l & 15);
    int slot = m * 4 + ((l >> 4) ^ ((m >> 1) & 3));
    aptr[i] = (const short8*)&Asd[slot * 8];
    int n = (w & 1) * 64 + i * 16 + (l & 15);
    int slotb = n * 4 + ((l >> 4) ^ ((n >> 1) & 3));
    bptr[i] = (const short8*)&Bsd[slotb * 8];
  }

  floatx4 acc[4][4];
#pragma unroll
  for (int i = 0; i < 4; i++)
#pragma unroll
    for (int j = 0; j < 4; j++) acc[i][j] = (floatx4){0.f, 0.f, 0.f, 0.f};

  for (int k0 = 0; k0 < K; k0 += 32) {
    __syncthreads();
    __builtin_amdgcn_global_load_lds((const __attribute__((address_space(1))) unsigned int*)(Ag0 + k0),
                                     (__attribute__((address_space(3))) unsigned int*)ALds0, 16, 0, 0);
    __builtin_amdgcn_global_load_lds((const __attribute__((address_space(1))) unsigned int*)(Ag1 + k0),
                                     (__attribute__((address_space(3))) unsigned int*)ALds1, 16, 0, 0);
    __builtin_amdgcn_global_load_lds((const __attribute__((address_space(1))) unsigned int*)(Bg0 + k0),
                                     (__attribute__((address_space(3))) unsigned int*)BLds0, 16, 0, 0);
    __builtin_amdgcn_global_load_lds((const __attribute__((address_space(1))) unsigned int*)(Bg1 + k0),
                                     (__attribute__((address_space(3))) unsigned int*)BLds1, 16, 0, 0);
    __syncthreads();
    short8 a[4], b[4];
#pragma unroll
    for (int i = 0; i < 4; i++) a[i] = *aptr[i];
#pragma unroll
    for (int j = 0; j < 4; j++) b[j] = *bptr[j];
#pragma unroll
    for (int i = 0; i < 4; i++)
#pragma unroll
      for (int j = 0; j < 4; j++)
        acc[i][j] = __builtin_amdgcn_mfma_f32_16x16x32_bf16(a[i], b[j], acc[i][j], 0, 0, 0);
  }

#pragma unroll
  for (int i = 0; i < 4; i++) {
#pragma unroll
    for (int j = 0; j < 4; j++) {
#pragma unroll
      for (int r = 0; r < 4; r++) {
        size_t row = brow + (w >> 1) * 64 + i * 16 + (l >> 4) * 4 + r;
        size_t col = bcol + (w & 1) * 64 + j * 16 + (l & 15);
        C[row * DFF + col] = f2bf(acc[i][j][r]);
      }
    }
  }
}

// ---------------- top-candidates per row: wave-per-token radix select ----------------
// Finds the 48th-largest bf16 score value, then collects ALL elements >= it
// (boundary ties included), capped at KMAX. Order of candidates is irrelevant
// (rescore ranks by exact fp32 score with index tie-break).
__global__ __launch_bounds__(256) void topk2_kernel(const unsigned short* __restrict__ scores,
    int* __restrict__ cand, int* __restrict__ cnt) {
  int wv = threadIdx.x >> 6, l = threadIdx.x & 63;
  int n = blockIdx.x * 4 + wv;
  const ushort8v* row = (const ushort8v*)(scores + (size_t)n * DFF);
  unsigned short key[64];
#pragma unroll
  for (int i = 0; i < 8; i++) {
    ushort8v v = row[l * 8 + i];
#pragma unroll
    for (int e = 0; e < 8; e++) {
      unsigned short u = v[e];
      key[i * 8 + e] = (u & 0x8000u) ? (unsigned short)(~u)
                                     : (unsigned short)(u | 0x8000u);
    }
  }
  // binary-search the 48th largest key value, MSB -> LSB
  unsigned int prefix = 0;
#pragma unroll
  for (int bit = 15; bit >= 0; bit--) {
    unsigned int probe = prefix | (1u << bit);
    int c = 0;
#pragma unroll
    for (int i = 0; i < 64; i++) c += (key[i] >= probe) ? 1 : 0;
#pragma unroll
    for (int s = 1; s < 64; s <<= 1) c += __shfl_xor(c, s);
    if (c >= KCAND) prefix = probe;
  }
  unsigned short thr = (unsigned short)prefix;
  // ballot compaction of all keys >= thr
  unsigned long long ltmask = (1ull << l) - 1ull;
  int base = 0;
  int* outp = cand + (size_t)n * KMAX;
#pragma unroll
  for (int i = 0; i < 64; i++) {
    bool p = key[i] >= thr;
    unsigned long long m = __ballot(p);
    if (p) {
      int pos = base + __popcll(m & ltmask);
      if (pos < KMAX) outp[pos] = l * 64 + i;
    }
    base += __popcll(m);
  }
  if (l == 0) cnt[n] = base < KMAX ? base : KMAX;
}

// ---------------- fp32 rescore of candidates -> exact top-32 set ----------------
__global__ __launch_bounds__(256) void rescore_kernel(const float* __restrict__ h,
    const float* __restrict__ w2f, const int* __restrict__ cand,
    const int* __restrict__ cnt, int* __restrict__ idx32) {
  __shared__ float sh[DM];
  __shared__ float sc[KMAX];
  __shared__ int sidx[KMAX];
  __shared__ int s_cnt;
  int n = blockIdx.x, tid = threadIdx.x;
  *(float4*)&sh[tid * 4] = *(const float4*)(h + (size_t)n * DM + tid * 4);
  if (tid == 0) s_cnt = cnt[n];
  if (tid < KMAX) { sidx[tid] = cand[(size_t)n * KMAX + tid]; sc[tid] = -INFINITY; }
  __syncthreads();
  int cntv = s_cnt;
  int w = tid >> 6, lane = tid & 63;
  for (int c = w; c < cntv; c += 4) {
    const float4* row = (const float4*)(w2f + (size_t)sidx[c] * DM);
    const float4* hp = (const float4*)sh;
    float s = 0.f;
#pragma unroll
    for (int t = 0; t < 4; t++) {
      float4 wv = row[t * 64 + lane];
      float4 hv = hp[t * 64 + lane];
      s = fmaf(wv.x, hv.x, s); s = fmaf(wv.y, hv.y, s);
      s = fmaf(wv.z, hv.z, s); s = fmaf(wv.w, hv.w, s);
    }
    for (int off = 32; off; off >>= 1) s += __shfl_xor(s, off);
    if (lane == 0) sc[c] = s;
  }
  __syncthreads();
  if (tid < cntv) {
    float st = sc[tid]; int it = sidx[tid];
    int rank = 0;
    for (int j = 0; j < KMAX; j++) {
      float sj = sc[j];
      rank += (sj > st) || (sj == st && sidx[j] < it);
    }
    if (rank < KSEL) idx32[(size_t)n * KSEL + rank] = it;
  }
}

// ------- per-neuron qkv table (bf16 out) -------
__global__ __launch_bounds__(384) void qkvtab_kernel(const float* __restrict__ nv,
    const float* __restrict__ ipw, const float* __restrict__ ipb,
    unsigned short* __restrict__ tab) {
  __shared__ float s_nv[8 * 128];
  int f0 = blockIdx.x * 8;
  int tid = threadIdx.x;
  for (int i = tid; i < 8 * 128; i += 384) s_nv[i] = nv[(size_t)f0 * 128 + i];
  __syncthreads();
  int row = tid;
  float bias = ipb[row];
  float acc[8];
#pragma unroll
  for (int ff = 0; ff < 8; ff++) acc[ff] = bias;
  const float* wr = ipw + (size_t)row * 128;
  for (int c = 0; c < 128; c++) {
    float w = wr[c];
#pragma unroll
    for (int ff = 0; ff < 8; ff++) acc[ff] = fmaf(s_nv[ff * 128 + c], w, acc[ff]);
  }
#pragma unroll
  for (int ff = 0; ff < 8; ff++) tab[(size_t)(f0 + ff) * 384 + row] = f2bf(acc[ff]);
}

// ---------------- fused per-token tail v2: 2 tokens/block, MFMA out_proj+gate ----------------
#define AOS 136   // LDS row stride (ushorts) for ao / attended
__global__ __launch_bounds__(256) void tail2_kernel(
    const float* __restrict__ xf, const unsigned short* __restrict__ pats_b,
    const unsigned short* __restrict__ dirs_b, const unsigned short* __restrict__ qtab_b,
    const int* __restrict__ idxs,
    const unsigned short* __restrict__ opwb, const float* __restrict__ opb,
    const unsigned short* __restrict__ w1b, const float* __restrict__ b1,
    const float* __restrict__ w2, const float* __restrict__ b2,
    float* __restrict__ out) {
  __shared__ float s_xf[2][1024];
  __shared__ unsigned short s_ao[64 * AOS];
  __shared__ unsigned short s_at[64 * AOS];
  __shared__ float s_base[64];
  __shared__ float s_coef[64];
  __shared__ int s_idx[64];

  int n0 = blockIdx.x * 2;
  int tid = threadIdx.x;
  int w = tid >> 6, l = tid & 63;

  if (tid < 64) s_idx[tid] = idxs[(size_t)n0 * 32 + tid];
#pragma unroll
  for (int t = 0; t < 2; t++)
    for (int i = tid; i < 1024; i += 256)
      s_xf[t][i] = xf[(size_t)(n0 + t) * 1024 + i];
  __syncthreads();

  // ---- base[t][j] = gelu(xf . pats[idx]) : (t,j,lq) = (tid>>7, (tid>>2)&31, tid&3)
  {
    int t = tid >> 7, j = (tid >> 2) & 31, lq = tid & 3;
    const ushort8v* pr = (const ushort8v*)(pats_b + (size_t)s_idx[t * 32 + j] * 1024);
    const float* xr = s_xf[t];
    float s = 0.f;
#pragma unroll 8
    for (int it = 0; it < 32; it++) {
      int g = it * 4 + lq;
      ushort8v pv = pr[g];
#pragma unroll
      for (int e = 0; e < 8; e++) s = fmaf(bf2f(pv[e]), xr[g * 8 + e], s);
    }
    s += __shfl_xor(s, 1);
    s += __shfl_xor(s, 2);
    if (lq == 0) s_base[t * 32 + j] = gelu_f(s);
  }

  // ---- attention: wave w -> token w>>1, head-quad w&1; 2 passes x 2 lane-half heads
  {
    int t = w >> 1, hq = w & 1, qj = l & 31;
    const int* myidx = &s_idx[t * 32];
#pragma unroll
    for (int p = 0; p < 2; p++) {
      int h0 = hq * 4 + p * 2 + (l >> 5);
      const ushort8v* qr = (const ushort8v*)(qtab_b + (size_t)myidx[qj] * 384 + h0 * 16);
      ushort8v q0 = qr[0], q1 = qr[1];
      float q[16];
#pragma unroll
      for (int e = 0; e < 8; e++) { q[e] = bf2f(q0[e]); q[8 + e] = bf2f(q1[e]); }
      float att[32];
#pragma unroll 8
      for (int kj = 0; kj < 32; kj++) {
        const ushort8v* kr = (const ushort8v*)(qtab_b + (size_t)myidx[kj] * 384 + 128 + h0 * 16);
        ushort8v k0 = kr[0], k1 = kr[1];
        float s = 0.f;
#pragma unroll
        for (int e = 0; e < 8; e++) s = fmaf(q[e], bf2f(k0[e]), s);
#pragma unroll
        for (int e = 0; e < 8; e++) s = fmaf(q[8 + e], bf2f(k1[e]), s);
        att[kj] = s * 0.25f;
      }
      float m = att[0];
#pragma unroll
      for (int k = 1; k < 32; k++) m = fmaxf(m, att[k]);
      float sum = 0.f;
#pragma unroll
      for (int k = 0; k < 32; k++) { att[k] = expf(att[k] - m); sum += att[k]; }
      float inv = 1.f / sum;
#pragma unroll
      for (int k = 0; k < 32; k++) att[k] *= inv;
      float o[16];
#pragma unroll
      for (int e = 0; e < 16; e++) o[e] = 0.f;
#pragma unroll 8
      for (int kj = 0; kj < 32; kj++) {
        const ushort8v* vr = (const ushort8v*)(qtab_b + (size_t)myidx[kj] * 384 + 256 + h0 * 16);
        ushort8v v0 = vr[0], v1 = vr[1];
        float a = att[kj];
#pragma unroll
        for (int e = 0; e < 8; e++) o[e] = fmaf(a, bf2f(v0[e]), o[e]);
#pragma unroll
        for (int e = 0; e < 8; e++) o[8 + e] = fmaf(a, bf2f(v1[e]), o[8 + e]);
      }
      ushort8v o0, o1;
#pragma unroll
      for (int e = 0; e < 8; e++) { o0[e] = f2bf(o[e]); o1[e] = f2bf(o[8 + e]); }
      ushort8v* ao = (ushort8v*)&s_ao[(t * 32 + qj) * AOS + h0 * 16];
      ao[0] = o0; ao[1] = o1;
    }
  }
  __syncthreads();

  // ---- out_proj MFMA: attended[64][128] = ao @ opwb^T + opb ; wave w -> m-tile w
  {
    floatx4 acc[8];
#pragma unroll
    for (int nt = 0; nt < 8; nt++) acc[nt] = (floatx4){0.f, 0.f, 0.f, 0.f};
#pragma unroll
    for (int kst = 0; kst < 4; kst++) {
      short8 a = *(const short8*)&s_ao[(w * 16 + (l & 15)) * AOS + kst * 32 + (l >> 4) * 8];
#pragma unroll
      for (int nt = 0; nt < 8; nt++) {
        short8 b = *(const short8*)&opwb[(size_t)(nt * 16 + (l & 15)) * 128 + kst * 32 + (l >> 4) * 8];
        acc[nt] = __builtin_amdgcn_mfma_f32_16x16x32_bf16(a, b, acc[nt], 0, 0, 0);
      }
    }
#pragma unroll
    for (int nt = 0; nt < 8; nt++) {
      int col = nt * 16 + (l & 15);
      float bias = opb[col];
#pragma unroll
      for (int r = 0; r < 4; r++) {
        int row = w * 16 + (l >> 4) * 4 + r;
        s_at[row * AOS + col] = f2bf(acc[nt][r] + bias);
      }
    }
  }
  __syncthreads();

  // ---- gate MFMA: hid[64][64] = gelu(attended @ w1b^T + b1); logit reduce in-reg
  {
    floatx4 acc[4];
#pragma unroll
    for (int nt = 0; nt < 4; nt++) acc[nt] = (floatx4){0.f, 0.f, 0.f, 0.f};
#pragma unroll
    for (int kst = 0; kst < 4; kst++) {
      short8 a = *(const short8*)&s_at[(w * 16 + (l & 15)) * AOS + kst * 32 + (l >> 4) * 8];
#pragma unroll
      for (int nt = 0; nt < 4; nt++) {
        short8 b = *(const short8*)&w1b[(size_t)(nt * 16 + (l & 15)) * 128 + kst * 32 + (l >> 4) * 8];
        acc[nt] = __builtin_amdgcn_mfma_f32_16x16x32_bf16(a, b, acc[nt], 0, 0, 0);
      }
    }
    float p[4] = {0.f, 0.f, 0.f, 0.f};
#pragma unroll
    for (int nt = 0; nt < 4; nt++) {
      int col = nt * 16 + (l & 15);
      float bb = b1[col], ww = w2[col];
#pragma unroll
      for (int r = 0; r < 4; r++)
        p[r] = fmaf(gelu_f(acc[nt][r] + bb), ww, p[r]);
    }
#pragma unroll
    for (int r = 0; r < 4; r++) {
      p[r] += __shfl_xor(p[r], 1);
      p[r] += __shfl_xor(p[r], 2);
      p[r] += __shfl_xor(p[r], 4);
      p[r] += __shfl_xor(p[r], 8);
    }
    if ((l & 15) == 0) {
      float b2v = b2[0];
#pragma unroll
      for (int r = 0; r < 4; r++) {
        int row = w * 16 + (l >> 4) * 4 + r;
        float sw = 1.f / (1.f + expf(-(p[r] + b2v)));
        s_coef[row] = s_base[row] * sw;
      }
    }
  }
  __syncthreads();

  // ---- output: out[t][d] = sum_j coef * dirs_b[idx[j]][d]
#pragma unroll
  for (int t = 0; t < 2; t++) {
    int d0 = tid * 4;
    float4 a = {0.f, 0.f, 0.f, 0.f};
#pragma unroll 8
    for (int j = 0; j < 32; j++) {
      float c = s_coef[t * 32 + j];
      ushort4v dv = *(const ushort4v*)&dirs_b[(size_t)s_idx[t * 32 + j] * 1024 + d0];
      a.x = fmaf(c, bf2f(dv.x), a.x);
      a.y = fmaf(c, bf2f(dv.y), a.y);
      a.z = fmaf(c, bf2f(dv.z), a.z);
      a.w = fmaf(c, bf2f(dv.w), a.w);
    }
    *(float4*)&out[(size_t)(n0 + t) * 1024 + d0] = a;
  }
}

extern "C" void kernel_launch(void* const* d_in, const int* in_sizes, int n_in,
                              void* d_out, int out_size, void* d_ws, size_t ws_size,
                              hipStream_t stream) {
  const float* x    = (const float*)d_in[0];
  const float* pats = (const float*)d_in[1];
  const float* nv   = (const float*)d_in[2];
  const float* dirs = (const float*)d_in[3];
  const float* rw1  = (const float*)d_in[4];
  const float* rw2  = (const float*)d_in[5];
  const float* lng  = (const float*)d_in[6];
  const float* lnb  = (const float*)d_in[7];
  const float* ipw  = (const float*)d_in[8];
  const float* ipb  = (const float*)d_in[9];
  const float* opw  = (const float*)d_in[10];
  const float* opb  = (const float*)d_in[11];
  const float* w1   = (const float*)d_in[12];
  const float* b1   = (const float*)d_in[13];
  const float* w2   = (const float*)d_in[14];
  const float* b2   = (const float*)d_in[15];
  float* out = (float*)d_out;

  const size_t MB = 1u << 20;
  char* ws = (char*)d_ws;
  float* xn            = (float*)(ws + 0);                 // 16 MB
  float* h             = (float*)(ws + 16 * MB);           // 16 MB
  unsigned short* sb   = (unsigned short*)(ws + 32 * MB);  // 32 MB (bf16 scores)
  unsigned short* qtab = (unsigned short*)(ws + 64 * MB);  // 3 MB
  unsigned short* hb   = (unsigned short*)(ws + 67 * MB);  // 8 MB
  unsigned short* w2b  = (unsigned short*)(ws + 75 * MB);  // 8 MB
  unsigned short* patsb= (unsigned short*)(ws + 83 * MB);  // 8 MB
  unsigned short* dirsb= (unsigned short*)(ws + 91 * MB);  // 8 MB
  unsigned short* opwb = (unsigned short*)(ws + 99 * MB);  // 32 KB
  unsigned short* w1b  = (unsigned short*)(ws + 99 * MB + 64 * 1024);  // 16 KB
  int* idx32           = (int*)(ws + 100 * MB);            // 512 KB
  int* cand            = (int*)(ws + 101 * MB);            // 1 MB (KMAX=64/token)
  int* cnt             = (int*)(ws + 102 * MB);            // 16 KB

  ln_kernel<<<N_TOK, 256, 0, stream>>>(x, lng, lnb, xn);
  gemm_nt<<<dim3(DM / 128, N_TOK / 128), 256, 0, stream>>>(xn, rw1, h, hb, N_TOK, DM, DM);
  cvt_bf16<<<(DFF * DM) / 1024, 256, 0, stream>>>(rw2, w2b);
  cvt_bf16<<<(DFF * DM) / 1024, 256, 0, stream>>>(pats, patsb);
  cvt_bf16<<<(DFF * DM) / 1024, 256, 0, stream>>>(dirs, dirsb);
  cvt_bf16<<<(DN * DN) / 1024, 256, 0, stream>>>(opw, opwb);
  cvt_bf16<<<(DN * DN / 2) / 1024, 256, 0, stream>>>(w1, w1b);
  gemm_bf<<<dim3(DFF / 128, N_TOK / 128), 256, 0, stream>>>(hb, w2b, sb);
  topk2_kernel<<<N_TOK / 4, 256, 0, stream>>>(sb, cand, cnt);
  rescore_kernel<<<N_TOK, 256, 0, stream>>>(h, rw2, cand, cnt, idx32);
  qkvtab_kernel<<<DFF / 8, 384, 0, stream>>>(nv, ipw, ipb, qtab);
  tail2_kernel<<<N_TOK / 2, 256, 0, stream>>>(x, patsb, dirsb, qtab, idx32,
                                              opwb, opb, w1b, b1, w2, b2, out);
}

// Round 5
// 615.241 us; speedup vs baseline: 3.0700x; 1.1270x over previous
//
#include <hip/hip_runtime.h>
#include <math.h>

#define N_TOK 4096
#define DM 1024
#define DFF 4096
#define DN 128
#define NH 8
#define HD 16
#define KSEL 32
#define KCAND 48
#define KMAX 64

typedef __attribute__((ext_vector_type(4))) float floatx4;
typedef __attribute__((ext_vector_type(8))) short short8;
typedef __attribute__((ext_vector_type(8))) unsigned short ushort8v;
typedef __attribute__((ext_vector_type(4))) unsigned short ushort4v;

__device__ __forceinline__ float gelu_f(float x) {
  return 0.5f * x * (1.0f + erff(x * 0.70710678118654752440f));
}
__device__ __forceinline__ float bf2f(unsigned short u) {
  union { unsigned int i; float f; } v; v.i = ((unsigned int)u) << 16; return v.f;
}
__device__ __forceinline__ unsigned short f2bf(float f) {
  unsigned int x = __float_as_uint(f);
  unsigned int r = (x + 0x7fffu + ((x >> 16) & 1u)) >> 16;
  return (unsigned short)r;
}

// ---------------- LayerNorm ----------------
__global__ __launch_bounds__(256) void ln_kernel(const float* __restrict__ x,
    const float* __restrict__ g, const float* __restrict__ b, float* __restrict__ xn) {
  int n = blockIdx.x, tid = threadIdx.x;
  const float* row = x + (size_t)n * DM;
  float s = 0.f, sq = 0.f;
  for (int i = tid; i < DM; i += 256) { float v = row[i]; s += v; sq += v * v; }
  for (int off = 32; off; off >>= 1) { s += __shfl_down(s, off); sq += __shfl_down(sq, off); }
  __shared__ float ss[4], ssq[4];
  __shared__ float s_mu, s_rs;
  int wid = tid >> 6;
  if ((tid & 63) == 0) { ss[wid] = s; ssq[wid] = sq; }
  __syncthreads();
  if (tid == 0) {
    float S = ss[0] + ss[1] + ss[2] + ss[3];
    float Q = ssq[0] + ssq[1] + ssq[2] + ssq[3];
    float mu = S * (1.f / DM);
    float var = Q * (1.f / DM) - mu * mu;
    s_mu = mu; s_rs = rsqrtf(var + 1e-5f);
  }
  __syncthreads();
  float mu = s_mu, rs = s_rs;
  float* o = xn + (size_t)n * DM;
  for (int i = tid; i < DM; i += 256) o[i] = (row[i] - mu) * rs * g[i] + b[i];
}

// ---------------- fp32 GEMM (gemm1): C = gelu(A@B^T), emits bf16 copy ----------------
// 512 threads, 128x128 tile, micro 4x8. 8 waves/CU (grid 256 = 1 block/CU).
__global__ __launch_bounds__(512) void gemm_nt(const float* __restrict__ A,
    const float* __restrict__ B, float* __restrict__ C, unsigned short* __restrict__ Cb,
    int M, int N, int K) {
  __shared__ float As[128 * 33];
  __shared__ float Bs[128 * 33];
  int tid = threadIdx.x;
  int tx = tid & 15, ty = tid >> 4;   // ty 0..31
  const float* Ab = A + (size_t)blockIdx.y * 128 * K;
  const float* Bb = B + (size_t)blockIdx.x * 128 * K;
  float acc[4][8] = {};
  for (int k0 = 0; k0 < K; k0 += 32) {
#pragma unroll
    for (int i = 0; i < 8; i++) {
      int l = tid + i * 512;
      int r = l >> 5, c = l & 31;
      As[r * 33 + c] = Ab[(size_t)r * K + k0 + c];
      Bs[r * 33 + c] = Bb[(size_t)r * K + k0 + c];
    }
    __syncthreads();
#pragma unroll
    for (int kk = 0; kk < 32; kk++) {
      float a[4], b[8];
#pragma unroll
      for (int i = 0; i < 4; i++) a[i] = As[(i * 32 + ty) * 33 + kk];
#pragma unroll
      for (int j = 0; j < 8; j++) b[j] = Bs[(j * 16 + tx) * 33 + kk];
#pragma unroll
      for (int i = 0; i < 4; i++)
#pragma unroll
        for (int j = 0; j < 8; j++)
          acc[i][j] = fmaf(a[i], b[j], acc[i][j]);
    }
    __syncthreads();
  }
#pragma unroll
  for (int i = 0; i < 4; i++) {
    size_t m = (size_t)blockIdx.y * 128 + i * 32 + ty;
#pragma unroll
    for (int j = 0; j < 8; j++) {
      size_t col = (size_t)blockIdx.x * 128 + j * 16 + tx;
      float v = gelu_f(acc[i][j]);
      C[m * N + col] = v;
      Cb[m * N + col] = f2bf(v);
    }
  }
}

// ---------------- generic fp32 -> bf16 convert ----------------
__global__ __launch_bounds__(256) void cvt_bf16(const float* __restrict__ in,
    unsigned short* __restrict__ out) {
  int i = (blockIdx.x * 256 + threadIdx.x) * 4;
  float4 v = *(const float4*)(in + i);
  ushort4v o = {f2bf(v.x), f2bf(v.y), f2bf(v.z), f2bf(v.w)};
  *(ushort4v*)(out + i) = o;
}

// ---------------- bf16 MFMA GEMM: scores_approx(bf16) = hb @ w2b^T ----------------
__global__ __launch_bounds__(256) void gemm_bf(const unsigned short* __restrict__ Ah,
    const unsigned short* __restrict__ Bh, unsigned short* __restrict__ C) {
  __shared__ short Asd[128 * 32];
  __shared__ short Bsd[128 * 32];
  const int K = 1024;
  int tid = threadIdx.x;
  int w = tid >> 6, l = tid & 63;
  size_t brow = (size_t)blockIdx.y * 128;
  size_t bcol = (size_t)blockIdx.x * 128;
  const short* Ab = (const short*)Ah + brow * K;
  const short* Bb = (const short*)Bh + bcol * K;

  int r0 = w * 32 + (l >> 2);
  int g0 = (l & 3) ^ ((r0 >> 1) & 3);
  const short* Ag0 = Ab + (size_t)r0 * K + g0 * 8;
  const short* Ag1 = Ab + (size_t)(r0 + 16) * K + g0 * 8;
  const short* Bg0 = Bb + (size_t)r0 * K + g0 * 8;
  const short* Bg1 = Bb + (size_t)(r0 + 16) * K + g0 * 8;
  short* ALds0 = &Asd[w * 1024];
  short* ALds1 = &Asd[w * 1024 + 512];
  short* BLds0 = &Bsd[w * 1024];
  short* BLds1 = &Bsd[w * 1024 + 512];

  const short8* aptr[4];
  const short8* bptr[4];
#pragma unroll
  for (int i = 0; i < 4; i++) {
    int m = (w >> 1) * 64 + i * 16 + (l & 15);
    int slot = m * 4 + ((l >> 4) ^ ((m >> 1) & 3));
    aptr[i] = (const short8*)&Asd[slot * 8];
    int n = (w & 1) * 64 + i * 16 + (l & 15);
    int slotb = n * 4 + ((l >> 4) ^ ((n >> 1) & 3));
    bptr[i] = (const short8*)&Bsd[slotb * 8];
  }

  floatx4 acc[4][4];
#pragma unroll
  for (int i = 0; i < 4; i++)
#pragma unroll
    for (int j = 0; j < 4; j++) acc[i][j] = (floatx4){0.f, 0.f, 0.f, 0.f};

  for (int k0 = 0; k0 < K; k0 += 32) {
    __syncthreads();
    __builtin_amdgcn_global_load_lds((const __attribute__((address_space(1))) unsigned int*)(Ag0 + k0),
                                     (__attribute__((address_space(3))) unsigned int*)ALds0, 16, 0, 0);
    __builtin_amdgcn_global_load_lds((const __attribute__((address_space(1))) unsigned int*)(Ag1 + k0),
                                     (__attribute__((address_space(3))) unsigned int*)ALds1, 16, 0, 0);
    __builtin_amdgcn_global_load_lds((const __attribute__((address_space(1))) unsigned int*)(Bg0 + k0),
                                     (__attribute__((address_space(3))) unsigned int*)BLds0, 16, 0, 0);
    __builtin_amdgcn_global_load_lds((const __attribute__((address_space(1))) unsigned int*)(Bg1 + k0),
                                     (__attribute__((address_space(3))) unsigned int*)BLds1, 16, 0, 0);
    __syncthreads();
    short8 a[4], b[4];
#pragma unroll
    for (int i = 0; i < 4; i++) a[i] = *aptr[i];
#pragma unroll
    for (int j = 0; j < 4; j++) b[j] = *bptr[j];
#pragma unroll
    for (int i = 0; i < 4; i++)
#pragma unroll
      for (int j = 0; j < 4; j++)
        acc[i][j] = __builtin_amdgcn_mfma_f32_16x16x32_bf16(a[i], b[j], acc[i][j], 0, 0, 0);
  }

#pragma unroll
  for (int i = 0; i < 4; i++) {
#pragma unroll
    for (int j = 0; j < 4; j++) {
#pragma unroll
      for (int r = 0; r < 4; r++) {
        size_t row = brow + (w >> 1) * 64 + i * 16 + (l >> 4) * 4 + r;
        size_t col = bcol + (w & 1) * 64 + j * 16 + (l & 15);
        C[row * DFF + col] = f2bf(acc[i][j][r]);
      }
    }
  }
}

// ---------------- top-candidates per row: wave-per-token radix select ----------------
__global__ __launch_bounds__(256) void topk2_kernel(const unsigned short* __restrict__ scores,
    int* __restrict__ cand, int* __restrict__ cnt) {
  int wv = threadIdx.x >> 6, l = threadIdx.x & 63;
  int n = blockIdx.x * 4 + wv;
  const ushort8v* row = (const ushort8v*)(scores + (size_t)n * DFF);
  unsigned short key[64];
#pragma unroll
  for (int i = 0; i < 8; i++) {
    ushort8v v = row[l * 8 + i];
#pragma unroll
    for (int e = 0; e < 8; e++) {
      unsigned short u = v[e];
      key[i * 8 + e] = (u & 0x8000u) ? (unsigned short)(~u)
                                     : (unsigned short)(u | 0x8000u);
    }
  }
  unsigned int prefix = 0;
#pragma unroll
  for (int bit = 15; bit >= 0; bit--) {
    unsigned int probe = prefix | (1u << bit);
    int c = 0;
#pragma unroll
    for (int i = 0; i < 64; i++) c += (key[i] >= probe) ? 1 : 0;
#pragma unroll
    for (int s = 1; s < 64; s <<= 1) c += __shfl_xor(c, s);
    if (c >= KCAND) prefix = probe;
  }
  unsigned short thr = (unsigned short)prefix;
  unsigned long long ltmask = (1ull << l) - 1ull;
  int base = 0;
  int* outp = cand + (size_t)n * KMAX;
#pragma unroll
  for (int i = 0; i < 64; i++) {
    bool p = key[i] >= thr;
    unsigned long long m = __ballot(p);
    if (p) {
      int pos = base + __popcll(m & ltmask);
      if (pos < KMAX) outp[pos] = l * 64 + i;
    }
    base += __popcll(m);
  }
  if (l == 0) cnt[n] = base < KMAX ? base : KMAX;
}

// ---------------- fp32 rescore of candidates -> exact top-32 set ----------------
__global__ __launch_bounds__(256) void rescore_kernel(const float* __restrict__ h,
    const float* __restrict__ w2f, const int* __restrict__ cand,
    const int* __restrict__ cnt, int* __restrict__ idx32) {
  __shared__ float sh[DM];
  __shared__ float sc[KMAX];
  __shared__ int sidx[KMAX];
  __shared__ int s_cnt;
  int n = blockIdx.x, tid = threadIdx.x;
  *(float4*)&sh[tid * 4] = *(const float4*)(h + (size_t)n * DM + tid * 4);
  if (tid == 0) s_cnt = cnt[n];
  if (tid < KMAX) { sidx[tid] = cand[(size_t)n * KMAX + tid]; sc[tid] = -INFINITY; }
  __syncthreads();
  int cntv = s_cnt;
  int w = tid >> 6, lane = tid & 63;
  for (int c = w; c < cntv; c += 4) {
    const float4* row = (const float4*)(w2f + (size_t)sidx[c] * DM);
    const float4* hp = (const float4*)sh;
    float s = 0.f;
#pragma unroll
    for (int t = 0; t < 4; t++) {
      float4 wv = row[t * 64 + lane];
      float4 hv = hp[t * 64 + lane];
      s = fmaf(wv.x, hv.x, s); s = fmaf(wv.y, hv.y, s);
      s = fmaf(wv.z, hv.z, s); s = fmaf(wv.w, hv.w, s);
    }
    for (int off = 32; off; off >>= 1) s += __shfl_xor(s, off);
    if (lane == 0) sc[c] = s;
  }
  __syncthreads();
  if (tid < cntv) {
    float st = sc[tid]; int it = sidx[tid];
    int rank = 0;
    for (int j = 0; j < KMAX; j++) {
      float sj = sc[j];
      rank += (sj > st) || (sj == st && sidx[j] < it);
    }
    if (rank < KSEL) idx32[(size_t)n * KSEL + rank] = it;
  }
}

// ------- per-neuron qkv table (bf16 out) -------
__global__ __launch_bounds__(384) void qkvtab_kernel(const float* __restrict__ nv,
    const float* __restrict__ ipw, const float* __restrict__ ipb,
    unsigned short* __restrict__ tab) {
  __shared__ float s_nv[8 * 128];
  int f0 = blockIdx.x * 8;
  int tid = threadIdx.x;
  for (int i = tid; i < 8 * 128; i += 384) s_nv[i] = nv[(size_t)f0 * 128 + i];
  __syncthreads();
  int row = tid;
  float bias = ipb[row];
  float acc[8];
#pragma unroll
  for (int ff = 0; ff < 8; ff++) acc[ff] = bias;
  const float* wr = ipw + (size_t)row * 128;
  for (int c = 0; c < 128; c++) {
    float w = wr[c];
#pragma unroll
    for (int ff = 0; ff < 8; ff++) acc[ff] = fmaf(s_nv[ff * 128 + c], w, acc[ff]);
  }
#pragma unroll
  for (int ff = 0; ff < 8; ff++) tab[(size_t)(f0 + ff) * 384 + row] = f2bf(acc[ff]);
}

// ---------------- tail v3: 1 token/block, 128 threads, k/v staged in LDS ----------------
#define AOS 132
__global__ __launch_bounds__(128) void tail3_kernel(
    const float* __restrict__ xf, const unsigned short* __restrict__ pats_b,
    const unsigned short* __restrict__ dirs_b, const unsigned short* __restrict__ qtab_b,
    const int* __restrict__ idxs,
    const unsigned short* __restrict__ opwb, const float* __restrict__ opb,
    const unsigned short* __restrict__ w1b, const float* __restrict__ b1,
    const float* __restrict__ w2, const float* __restrict__ b2,
    float* __restrict__ out) {
  __shared__ unsigned short s_kv[2 * 32 * 128];   // k rows then v rows; later aliased as s_at
  __shared__ unsigned short s_xf[1024];           // x row, bf16
  __shared__ unsigned short s_ao[32 * AOS];
  __shared__ float s_base[32];
  __shared__ float s_coef[32];
  __shared__ int s_idx[32];
  unsigned short* s_k = s_kv;
  unsigned short* s_v = s_kv + 32 * 128;
  unsigned short* s_at = s_kv;                    // 32*AOS = 4224 <= 8192 shorts

  int n = blockIdx.x, tid = threadIdx.x;
  int w = tid >> 6, l = tid & 63;

  if (tid < 32) s_idx[tid] = idxs[(size_t)n * 32 + tid];
  // x row -> bf16 LDS (8 elems/thread)
  {
    const float4* xr = (const float4*)(xf + (size_t)n * DM);
    float4 a = xr[tid * 2], b = xr[tid * 2 + 1];
    ushort8v o = {f2bf(a.x), f2bf(a.y), f2bf(a.z), f2bf(a.w),
                  f2bf(b.x), f2bf(b.y), f2bf(b.z), f2bf(b.w)};
    *(ushort8v*)&s_xf[tid * 8] = o;
  }
  __syncthreads();   // s_idx ready for staging/base

  // stage k+v rows into LDS: 1024 16B-chunks, 8 per thread
#pragma unroll
  for (int p = 0; p < 8; p++) {
    int i = p * 128 + tid;
    int j = i >> 5, c = i & 31;
    int half = c >> 4, cc = c & 15;
    ushort8v v = *(const ushort8v*)(qtab_b + (size_t)s_idx[j] * 384 + 128 + half * 128 + cc * 8);
    *(ushort8v*)&s_kv[half * 4096 + j * 128 + cc * 8] = v;
  }

  // base[j] = gelu(xf . pats[idx[j]]) : 32 groups x 4 lanes
  {
    int j = tid >> 2, lq = tid & 3;
    const ushort8v* pr = (const ushort8v*)(pats_b + (size_t)s_idx[j] * 1024);
    float s = 0.f;
#pragma unroll 8
    for (int it = 0; it < 32; it++) {
      int g = it * 4 + lq;
      ushort8v pv = pr[g];
      const ushort8v xv = *(const ushort8v*)&s_xf[g * 8];
#pragma unroll
      for (int e = 0; e < 8; e++) s = fmaf(bf2f(pv[e]), bf2f(xv[e]), s);
    }
    s += __shfl_xor(s, 1);
    s += __shfl_xor(s, 2);
    if (lq == 0) s_base[j] = gelu_f(s);
  }
  __syncthreads();   // k/v staged

  // attention: wave w handles heads w*4..w*4+3 (2 passes x 2 lane-half heads)
  {
    int qj = l & 31;
#pragma unroll
    for (int p = 0; p < 2; p++) {
      int h0 = w * 4 + p * 2 + (l >> 5);
      const ushort8v* qr = (const ushort8v*)(qtab_b + (size_t)s_idx[qj] * 384 + h0 * 16);
      ushort8v q0 = qr[0], q1 = qr[1];
      float q[16];
#pragma unroll
      for (int e = 0; e < 8; e++) { q[e] = bf2f(q0[e]); q[8 + e] = bf2f(q1[e]); }
      float att[32];
#pragma unroll 8
      for (int kj = 0; kj < 32; kj++) {
        const ushort8v* kr = (const ushort8v*)&s_k[kj * 128 + h0 * 16];
        ushort8v k0 = kr[0], k1 = kr[1];
        float s = 0.f;
#pragma unroll
        for (int e = 0; e < 8; e++) s = fmaf(q[e], bf2f(k0[e]), s);
#pragma unroll
        for (int e = 0; e < 8; e++) s = fmaf(q[8 + e], bf2f(k1[e]), s);
        att[kj] = s * 0.25f;
      }
      float m = att[0];
#pragma unroll
      for (int k = 1; k < 32; k++) m = fmaxf(m, att[k]);
      float sum = 0.f;
#pragma unroll
      for (int k = 0; k < 32; k++) { att[k] = expf(att[k] - m); sum += att[k]; }
      float inv = 1.f / sum;
#pragma unroll
      for (int k = 0; k < 32; k++) att[k] *= inv;
      float o[16];
#pragma unroll
      for (int e = 0; e < 16; e++) o[e] = 0.f;
#pragma unroll 8
      for (int kj = 0; kj < 32; kj++) {
        const ushort8v* vr = (const ushort8v*)&s_v[kj * 128 + h0 * 16];
        ushort8v v0 = vr[0], v1 = vr[1];
        float a = att[kj];
#pragma unroll
        for (int e = 0; e < 8; e++) o[e] = fmaf(a, bf2f(v0[e]), o[e]);
#pragma unroll
        for (int e = 0; e < 8; e++) o[8 + e] = fmaf(a, bf2f(v1[e]), o[8 + e]);
      }
      ushort8v o0, o1;
#pragma unroll
      for (int e = 0; e < 8; e++) { o0[e] = f2bf(o[e]); o1[e] = f2bf(o[8 + e]); }
      ushort8v* ao = (ushort8v*)&s_ao[qj * AOS + h0 * 16];
      ao[0] = o0; ao[1] = o1;
    }
  }
  __syncthreads();   // attention done; s_kv dead -> s_at usable

  // out_proj MFMA: attended[32][128] = ao @ opwb^T + opb ; wave w -> rows w*16..
  {
    floatx4 acc[8];
#pragma unroll
    for (int nt = 0; nt < 8; nt++) acc[nt] = (floatx4){0.f, 0.f, 0.f, 0.f};
#pragma unroll
    for (int kst = 0; kst < 4; kst++) {
      short8 a = *(const short8*)&s_ao[(w * 16 + (l & 15)) * AOS + kst * 32 + (l >> 4) * 8];
#pragma unroll
      for (int nt = 0; nt < 8; nt++) {
        short8 b = *(const short8*)&opwb[(size_t)(nt * 16 + (l & 15)) * 128 + kst * 32 + (l >> 4) * 8];
        acc[nt] = __builtin_amdgcn_mfma_f32_16x16x32_bf16(a, b, acc[nt], 0, 0, 0);
      }
    }
#pragma unroll
    for (int nt = 0; nt < 8; nt++) {
      int col = nt * 16 + (l & 15);
      float bias = opb[col];
#pragma unroll
      for (int r = 0; r < 4; r++) {
        int row = w * 16 + (l >> 4) * 4 + r;
        s_at[row * AOS + col] = f2bf(acc[nt][r] + bias);
      }
    }
  }
  __syncthreads();

  // gate MFMA: hid[32][64] = gelu(attended @ w1b^T + b1); logit reduced in-register
  {
    floatx4 acc[4];
#pragma unroll
    for (int nt = 0; nt < 4; nt++) acc[nt] = (floatx4){0.f, 0.f, 0.f, 0.f};
#pragma unroll
    for (int kst = 0; kst < 4; kst++) {
      short8 a = *(const short8*)&s_at[(w * 16 + (l & 15)) * AOS + kst * 32 + (l >> 4) * 8];
#pragma unroll
      for (int nt = 0; nt < 4; nt++) {
        short8 b = *(const short8*)&w1b[(size_t)(nt * 16 + (l & 15)) * 128 + kst * 32 + (l >> 4) * 8];
        acc[nt] = __builtin_amdgcn_mfma_f32_16x16x32_bf16(a, b, acc[nt], 0, 0, 0);
      }
    }
    float p[4] = {0.f, 0.f, 0.f, 0.f};
#pragma unroll
    for (int nt = 0; nt < 4; nt++) {
      int col = nt * 16 + (l & 15);
      float bb = b1[col], ww = w2[col];
#pragma unroll
      for (int r = 0; r < 4; r++)
        p[r] = fmaf(gelu_f(acc[nt][r] + bb), ww, p[r]);
    }
#pragma unroll
    for (int r = 0; r < 4; r++) {
      p[r] += __shfl_xor(p[r], 1);
      p[r] += __shfl_xor(p[r], 2);
      p[r] += __shfl_xor(p[r], 4);
      p[r] += __shfl_xor(p[r], 8);
    }
    if ((l & 15) == 0) {
      float b2v = b2[0];
#pragma unroll
      for (int r = 0; r < 4; r++) {
        int row = w * 16 + (l >> 4) * 4 + r;
        float sw = 1.f / (1.f + expf(-(p[r] + b2v)));
        s_coef[row] = s_base[row] * sw;
      }
    }
  }
  __syncthreads();

  // output: out[n][d] = sum_j coef[j] * dirs_b[idx[j]][d]
#pragma unroll
  for (int ii = 0; ii < 2; ii++) {
    int d0 = (ii * 128 + tid) * 4;
    float4 a = {0.f, 0.f, 0.f, 0.f};
#pragma unroll 8
    for (int j = 0; j < 32; j++) {
      float c = s_coef[j];
      ushort4v dv = *(const ushort4v*)&dirs_b[(size_t)s_idx[j] * 1024 + d0];
      a.x = fmaf(c, bf2f(dv.x), a.x);
      a.y = fmaf(c, bf2f(dv.y), a.y);
      a.z = fmaf(c, bf2f(dv.z), a.z);
      a.w = fmaf(c, bf2f(dv.w), a.w);
    }
    *(float4*)&out[(size_t)n * 1024 + d0] = a;
  }
}

extern "C" void kernel_launch(void* const* d_in, const int* in_sizes, int n_in,
                              void* d_out, int out_size, void* d_ws, size_t ws_size,
                              hipStream_t stream) {
  const float* x    = (const float*)d_in[0];
  const float* pats = (const float*)d_in[1];
  const float* nv   = (const float*)d_in[2];
  const float* dirs = (const float*)d_in[3];
  const float* rw1  = (const float*)d_in[4];
  const float* rw2  = (const float*)d_in[5];
  const float* lng  = (const float*)d_in[6];
  const float* lnb  = (const float*)d_in[7];
  const float* ipw  = (const float*)d_in[8];
  const float* ipb  = (const float*)d_in[9];
  const float* opw  = (const float*)d_in[10];
  const float* opb  = (const float*)d_in[11];
  const float* w1   = (const float*)d_in[12];
  const float* b1   = (const float*)d_in[13];
  const float* w2   = (const float*)d_in[14];
  const float* b2   = (const float*)d_in[15];
  float* out = (float*)d_out;

  const size_t MB = 1u << 20;
  char* ws = (char*)d_ws;
  float* xn            = (float*)(ws + 0);                 // 16 MB
  float* h             = (float*)(ws + 16 * MB);           // 16 MB
  unsigned short* sb   = (unsigned short*)(ws + 32 * MB);  // 32 MB (bf16 scores)
  unsigned short* qtab = (unsigned short*)(ws + 64 * MB);  // 3 MB
  unsigned short* hb   = (unsigned short*)(ws + 67 * MB);  // 8 MB
  unsigned short* w2b  = (unsigned short*)(ws + 75 * MB);  // 8 MB
  unsigned short* patsb= (unsigned short*)(ws + 83 * MB);  // 8 MB
  unsigned short* dirsb= (unsigned short*)(ws + 91 * MB);  // 8 MB
  unsigned short* opwb = (unsigned short*)(ws + 99 * MB);  // 32 KB
  unsigned short* w1b  = (unsigned short*)(ws + 99 * MB + 64 * 1024);  // 16 KB
  int* idx32           = (int*)(ws + 100 * MB);            // 512 KB
  int* cand            = (int*)(ws + 101 * MB);            // 1 MB
  int* cnt             = (int*)(ws + 102 * MB);            // 16 KB

  ln_kernel<<<N_TOK, 256, 0, stream>>>(x, lng, lnb, xn);
  gemm_nt<<<dim3(DM / 128, N_TOK / 128), 512, 0, stream>>>(xn, rw1, h, hb, N_TOK, DM, DM);
  cvt_bf16<<<(DFF * DM) / 1024, 256, 0, stream>>>(rw2, w2b);
  cvt_bf16<<<(DFF * DM) / 1024, 256, 0, stream>>>(pats, patsb);
  cvt_bf16<<<(DFF * DM) / 1024, 256, 0, stream>>>(dirs, dirsb);
  cvt_bf16<<<(DN * DN) / 1024, 256, 0, stream>>>(opw, opwb);
  cvt_bf16<<<(DN * DN / 2) / 1024, 256, 0, stream>>>(w1, w1b);
  gemm_bf<<<dim3(DFF / 128, N_TOK / 128), 256, 0, stream>>>(hb, w2b, sb);
  topk2_kernel<<<N_TOK / 4, 256, 0, stream>>>(sb, cand, cnt);
  rescore_kernel<<<N_TOK, 256, 0, stream>>>(h, rw2, cand, cnt, idx32);
  qkvtab_kernel<<<DFF / 8, 384, 0, stream>>>(nv, ipw, ipb, qtab);
  tail3_kernel<<<N_TOK, 128, 0, stream>>>(x, patsb, dirsb, qtab, idx32,
                                          opwb, opb, w1b, b1, w2, b2, out);
}